// Round 3
// baseline (140.758 us; speedup 1.0000x reference)
//
#include <hip/hip_runtime.h>

#define D_MODEL 1024
#define SEQ     2048
#define BATCH   2
#define NH      16

using u16 = unsigned short;
typedef __bf16 bf16x8 __attribute__((ext_vector_type(8)));
typedef float  f32x4  __attribute__((ext_vector_type(4)));

__device__ __forceinline__ u16 f2bf(float f){
  union { __bf16 h; u16 u; } v; v.h = (__bf16)f; return v.u;
}

__device__ __forceinline__ void gload_lds16(const void* g, void* l){
  __builtin_amdgcn_global_load_lds(
      (const __attribute__((address_space(1))) void*)g,
      (__attribute__((address_space(3))) void*)l, 16, 0, 0);
}

// ---------- kernel 1: fp32 -> bf16 (X) ----------
__global__ __launch_bounds__(256) void k_cvt(const float* __restrict__ in,
                                             u16* __restrict__ out, int n4){
  int i = blockIdx.x*256 + threadIdx.x;
  if (i >= n4) return;
  float4 v = ((const float4*)in)[i];
  ushort4 o; o.x=f2bf(v.x); o.y=f2bf(v.y); o.z=f2bf(v.z); o.w=f2bf(v.w);
  ((ushort4*)out)[i] = o;
}

// ---------- kernel 2: weight fp32[K][N] -> bf16 transposed [N][K] ----------
__global__ __launch_bounds__(256) void k_cvt_w_t(
    const float* __restrict__ wq, const float* __restrict__ wk,
    const float* __restrict__ wv, const float* __restrict__ w0,
    u16* __restrict__ oq, u16* __restrict__ ok,
    u16* __restrict__ ov, u16* __restrict__ o0){
  const float* W; u16* O;
  if      (blockIdx.z==0){W=wq;O=oq;}
  else if (blockIdx.z==1){W=wk;O=ok;}
  else if (blockIdx.z==2){W=wv;O=ov;}
  else               {W=w0;O=o0;}
  __shared__ float T[64][65];
  int t = threadIdx.x;
  int r0 = t>>4, cb = (t&15)*4;
  int kt = blockIdx.y*64, nt = blockIdx.x*64;
  #pragma unroll
  for (int j=0;j<4;++j){
    int r = r0 + j*16;
    float4 v = *(const float4*)(W + (size_t)(kt + r)*1024 + nt + cb);
    T[r][cb] = v.x; T[r][cb+1] = v.y; T[r][cb+2] = v.z; T[r][cb+3] = v.w;
  }
  __syncthreads();
  #pragma unroll
  for (int j=0;j<4;++j){
    int rn = r0 + j*16;
    ushort4 o;
    o.x = f2bf(T[cb  ][rn]); o.y = f2bf(T[cb+1][rn]);
    o.z = f2bf(T[cb+2][rn]); o.w = f2bf(T[cb+3][rn]);
    *(ushort4*)(O + (size_t)(nt + rn)*1024 + kt + cb) = o;
  }
}

// ---------- kernel 3/6: bf16 GEMM  C[M,N] = A[M,K] @ Bt[N,K]^T ----------
// 64x128 tile (occupancy: 6 blocks/CU QKV, LDS 24KB), 2-phase dbuf.
template<int MODE>
__global__ __launch_bounds__(256) void k_gemm(
    const u16* __restrict__ A,
    const u16* __restrict__ B0, const u16* __restrict__ B1, const u16* __restrict__ B2,
    u16* O0, u16* O1, u16* O2, float* OF, float scale0, int N, int K)
{
  const u16* Bt = B0; u16* Ob = O0; float scl = 1.0f;
  if (MODE == 0){
    if      (blockIdx.z == 1){ Bt = B1; Ob = O1; }
    else if (blockIdx.z == 2){ Bt = B2; Ob = O2; }
    else scl = scale0;
  }
  const int bm = blockIdx.y*64, bn = blockIdx.x*128;
  const int lane = threadIdx.x & 63, w = threadIdx.x >> 6;
  const int hi = lane >> 4, c = lane & 15;
  const int wr = w >> 1, wc = w & 1;

  __shared__ u16 As[2][64*32];
  __shared__ u16 Bs[2][128*32];

  const int i0 = 2*w, i1 = 2*w+1;
  const int cA = (lane&3)*8;
  const u16* aS  = A  + (size_t)(bm + w*16  + (lane>>2))*K + cA;
  const u16* bS0 = Bt + (size_t)(bn + i0*16 + (lane>>2))*K + cA;
  const u16* bS1 = Bt + (size_t)(bn + i1*16 + (lane>>2))*K + cA;

  auto stage = [&](int buf, int kk){
    gload_lds16(aS  + kk, As[buf] + w*512);
    gload_lds16(bS0 + kk, Bs[buf] + i0*512);
    gload_lds16(bS1 + kk, Bs[buf] + i1*512);
  };

  f32x4 acc[2][4];
  #pragma unroll
  for (int mi=0;mi<2;++mi)
    #pragma unroll
    for (int ni=0;ni<4;++ni) acc[mi][ni] = (f32x4){0.f,0.f,0.f,0.f};

  stage(0, 0);
  __syncthreads();
  int cur = 0;
  for (int kk = 0; kk < K; kk += 32){
    if (kk + 32 < K) stage(cur^1, kk + 32);
    const u16* as = As[cur];
    const u16* bs = Bs[cur];
    bf16x8 af[2], bfr[4];
    #pragma unroll
    for (int mi=0;mi<2;++mi)
      af[mi] = *(const bf16x8*)(as + (wr*32 + mi*16 + c)*32 + hi*8);
    #pragma unroll
    for (int ni=0;ni<4;++ni)
      bfr[ni] = *(const bf16x8*)(bs + (wc*64 + ni*16 + c)*32 + hi*8);
    #pragma unroll
    for (int mi=0;mi<2;++mi)
      #pragma unroll
      for (int ni=0;ni<4;++ni)
        acc[mi][ni] = __builtin_amdgcn_mfma_f32_16x16x32_bf16(af[mi], bfr[ni], acc[mi][ni], 0, 0, 0);
    __syncthreads();
    cur ^= 1;
  }
  #pragma unroll
  for (int mi=0;mi<2;++mi){
    #pragma unroll
    for (int ni=0;ni<4;++ni){
      int row = bm + wr*32 + mi*16 + hi*4;
      int col = bn + wc*64 + ni*16 + c;
      #pragma unroll
      for (int r=0;r<4;++r){
        if (MODE == 0) Ob[(size_t)(row + r)*N + col] = f2bf(acc[mi][ni][r] * scl);
        else           OF[(size_t)(row + r)*N + col] = acc[mi][ni][r];
      }
    }
  }
}

// ---------- kernel 4: V [B*S, H*64] -> Vt [B*H][64][S] ----------
__global__ __launch_bounds__(256) void k_trans_v(const u16* __restrict__ V,
                                                 u16* __restrict__ Vt){
  int st = blockIdx.x, bh = blockIdx.y;
  int b = bh >> 4, h = bh & 15;
  __shared__ u16 T[64][80];
  int t = threadIdx.x;
  {
    int s = t >> 2, dc = (t & 3)*16;
    const u16* src = V + (size_t)(b*SEQ + st*64 + s)*D_MODEL + h*64 + dc;
    *(uint4*)&T[s][dc]   = *(const uint4*)(src);
    *(uint4*)&T[s][dc+8] = *(const uint4*)(src + 8);
  }
  __syncthreads();
  {
    int d = t >> 2, sc = (t & 3)*16;
    u16* dst = Vt + ((size_t)bh*64 + d)*SEQ + st*64 + sc;
    uint4 w0, w1;
    w0.x = (unsigned)T[sc+ 0][d] | ((unsigned)T[sc+ 1][d] << 16);
    w0.y = (unsigned)T[sc+ 2][d] | ((unsigned)T[sc+ 3][d] << 16);
    w0.z = (unsigned)T[sc+ 4][d] | ((unsigned)T[sc+ 5][d] << 16);
    w0.w = (unsigned)T[sc+ 6][d] | ((unsigned)T[sc+ 7][d] << 16);
    w1.x = (unsigned)T[sc+ 8][d] | ((unsigned)T[sc+ 9][d] << 16);
    w1.y = (unsigned)T[sc+10][d] | ((unsigned)T[sc+11][d] << 16);
    w1.z = (unsigned)T[sc+12][d] | ((unsigned)T[sc+13][d] << 16);
    w1.w = (unsigned)T[sc+14][d] | ((unsigned)T[sc+15][d] << 16);
    *(uint4*)(dst)     = w0;
    *(uint4*)(dst + 8) = w1;
  }
}

// ---------- kernel 5: attention ----------
// Q pre-scaled by log2(e)/sqrt(S); |logit| small -> no max subtraction.
// All LDS addresses hoisted to registers + compile-time ds offsets
// (unroll-by-2 over the double buffer makes buf*8192 an immediate).
// Row-sum l computed by MFMA with all-ones B (every lane gets full row sum).
__global__ __launch_bounds__(256, 4) void k_attn(const u16* __restrict__ Q,
                                                 const u16* __restrict__ Kg,
                                                 const u16* __restrict__ Vt,
                                                 u16* __restrict__ AO)
{
  const int qt = blockIdx.x, bh = blockIdx.y;
  const int b = bh >> 4, h = bh & 15;
  const int lane = threadIdx.x & 63, w = threadIdx.x >> 6;
  const int hi = lane >> 4, c = lane & 15;

  __shared__ u16 Ks[2][64*64];   // [key][dim], rows 128B, source-swizzled
  __shared__ u16 Vs[2][64*64];   // [dim][key], rows 128B, source-swizzled
  __shared__ u16 Ps[4][16*64];   // per-wave P bounce, rows 128B, swizzled

  const size_t qrow = (size_t)(b*SEQ + qt*64 + w*16 + c);
  const bf16x8 qf0 = *(const bf16x8*)(Q + qrow*D_MODEL + h*64 + hi*8);
  const bf16x8 qf1 = *(const bf16x8*)(Q + qrow*D_MODEL + h*64 + 32 + hi*8);

  bf16x8 ones;
  #pragma unroll
  for (int j=0;j<8;++j) ones[j] = (__bf16)1.0f;

  f32x4 acc_o[4];
  #pragma unroll
  for (int n=0;n<4;++n) acc_o[n] = (f32x4){0.f,0.f,0.f,0.f};
  f32x4 acc_l = (f32x4){0.f,0.f,0.f,0.f};

  // staging sources (pre-swizzled global addresses, LDS linear)
  const int i0 = 2*w, i1 = i0+1;
  const int r0 = i0*8 + (lane>>3), r1 = i1*8 + (lane>>3);
  const int sb0 = ((((lane&7)*16) ^ ((r0&7)<<4)) >> 1);
  const int sb1 = ((((lane&7)*16) ^ ((r1&7)<<4)) >> 1);
  const u16* kS0 = Kg + (size_t)(b*SEQ + r0)*D_MODEL + h*64 + sb0;
  const u16* kS1 = Kg + (size_t)(b*SEQ + r1)*D_MODEL + h*64 + sb1;
  const u16* vS0 = Vt + ((size_t)bh*64 + r0)*SEQ + sb0;
  const u16* vS1 = Vt + ((size_t)bh*64 + r1)*SEQ + sb1;

  auto stage = [&](int buf){
    gload_lds16(kS0, Ks[buf] + i0*512);
    gload_lds16(kS1, Ks[buf] + i1*512);
    gload_lds16(vS0, Vs[buf] + i0*512);
    gload_lds16(vS1, Vs[buf] + i1*512);
    kS0 += 64*D_MODEL; kS1 += 64*D_MODEL; vS0 += 64; vS1 += 64;
  };

  // hoisted LDS read bases: tile t / n-block at compile-time offset t*2048,
  // chunk at +64B (separate base due to XOR), buf at +8192.
  const int swz = ((c&7)<<4);
  const char* kr0 = (const char*)&Ks[0][0] + c*128 + (( 0 + hi*16) ^ swz);
  const char* kr1 = (const char*)&Ks[0][0] + c*128 + ((64 + hi*16) ^ swz);
  const char* vr0 = (const char*)&Vs[0][0] + c*128 + (( 0 + hi*16) ^ swz);
  const char* vr1 = (const char*)&Vs[0][0] + c*128 + ((64 + hi*16) ^ swz);
  char* pbase = (char*)&Ps[w][0];
  const char* pr0 = pbase + c*128 + (( 0 + hi*16) ^ swz);
  const char* pr1 = pbase + c*128 + ((64 + hi*16) ^ swz);
  // P-write offsets (static-indexed -> registers)
  int wa[16];
  #pragma unroll
  for (int i=0;i<4;++i){
    int m = hi*4 + i;
    #pragma unroll
    for (int t=0;t<4;++t)
      wa[i*4+t] = m*128 + ((((t*16 + c)*2)) ^ ((m&7)<<4));
  }

  auto body = [&](int buf){
    const int bo = buf*8192;
    f32x4 s[4];
    #pragma unroll
    for (int t=0;t<4;++t) s[t] = (f32x4){0.f,0.f,0.f,0.f};
    __builtin_amdgcn_s_setprio(1);
    #pragma unroll
    for (int t=0;t<4;++t){
      bf16x8 kf0 = *(const bf16x8*)(kr0 + bo + t*2048);
      bf16x8 kf1 = *(const bf16x8*)(kr1 + bo + t*2048);
      s[t] = __builtin_amdgcn_mfma_f32_16x16x32_bf16(qf0, kf0, s[t], 0,0,0);
      s[t] = __builtin_amdgcn_mfma_f32_16x16x32_bf16(qf1, kf1, s[t], 0,0,0);
    }
    __builtin_amdgcn_s_setprio(0);

    #pragma unroll
    for (int t=0;t<4;++t){
      #pragma unroll
      for (int i=0;i<4;++i){
        float p = __builtin_amdgcn_exp2f(s[t][i]);
        *(u16*)(pbase + wa[i*4+t]) = f2bf(p);
      }
    }

    bf16x8 pa0 = *(const bf16x8*)pr0;
    bf16x8 pa1 = *(const bf16x8*)pr1;
    acc_l = __builtin_amdgcn_mfma_f32_16x16x32_bf16(pa0, ones, acc_l, 0,0,0);
    acc_l = __builtin_amdgcn_mfma_f32_16x16x32_bf16(pa1, ones, acc_l, 0,0,0);
    __builtin_amdgcn_s_setprio(1);
    #pragma unroll
    for (int n=0;n<4;++n){
      bf16x8 v0 = *(const bf16x8*)(vr0 + bo + n*2048);
      bf16x8 v1 = *(const bf16x8*)(vr1 + bo + n*2048);
      acc_o[n] = __builtin_amdgcn_mfma_f32_16x16x32_bf16(pa0, v0, acc_o[n], 0,0,0);
      acc_o[n] = __builtin_amdgcn_mfma_f32_16x16x32_bf16(pa1, v1, acc_o[n], 0,0,0);
    }
    __builtin_amdgcn_s_setprio(0);
  };

  stage(0);
  __syncthreads();
  #pragma unroll 1
  for (int u = 0; u < SEQ/128; ++u){
    stage(1);
    body(0);
    __syncthreads();
    if (u != SEQ/128 - 1) stage(0);
    body(1);
    __syncthreads();
  }

  size_t obase = (size_t)(b*SEQ + qt*64 + w*16 + hi*4)*D_MODEL + h*64;
  #pragma unroll
  for (int r=0;r<4;++r){
    float inv = 1.0f / acc_l[r];
    #pragma unroll
    for (int n=0;n<4;++n)
      AO[obase + (size_t)r*D_MODEL + n*16 + c] = f2bf(acc_o[n][r] * inv);
  }
}

extern "C" void kernel_launch(void* const* d_in, const int* in_sizes, int n_in,
                              void* d_out, int out_size, void* d_ws, size_t ws_size,
                              hipStream_t stream)
{
  const float* X  = (const float*)d_in[0];
  const float* Wq = (const float*)d_in[1];
  const float* Wk = (const float*)d_in[2];
  const float* Wv = (const float*)d_in[3];
  const float* W0 = (const float*)d_in[4];
  float* out = (float*)d_out;

  char* ws = (char*)d_ws;
  const size_t MB = 1024*1024;
  u16* Xb  = (u16*)(ws);            // 8 MB  [4096,1024]
  u16* WqT = (u16*)(ws +  8*MB);    // 2 MB  [N,K]
  u16* WkT = (u16*)(ws + 10*MB);
  u16* WvT = (u16*)(ws + 12*MB);
  u16* W0T = (u16*)(ws + 14*MB);
  u16* Qb  = (u16*)(ws + 16*MB);    // 8 MB (pre-scaled by log2e/sqrt(S))
  u16* Kb  = (u16*)(ws + 24*MB);    // 8 MB
  u16* Vb  = (u16*)(ws + 32*MB);    // 8 MB
  u16* Vt  = (u16*)(ws + 40*MB);    // 8 MB [B*H][64][S]
  u16* AO  = Vb;                    // reuse: Vb dead after transpose

  const float scaleQ = 1.4426950408889634f / sqrtf((float)SEQ);
  const int M = BATCH*SEQ;

  k_cvt<<<dim3((M*D_MODEL/4 + 255)/256), 256, 0, stream>>>(X, Xb, M*D_MODEL/4);
  k_cvt_w_t<<<dim3(16,16,4), 256, 0, stream>>>(Wq, Wk, Wv, W0, WqT, WkT, WvT, W0T);
  k_gemm<0><<<dim3(D_MODEL/128, M/64, 3), 256, 0, stream>>>(
      Xb, WqT, WkT, WvT, Qb, Kb, Vb, nullptr, scaleQ, D_MODEL, D_MODEL);
  k_trans_v<<<dim3(SEQ/64, BATCH*NH), 256, 0, stream>>>(Vb, Vt);
  k_attn<<<dim3(SEQ/64, BATCH*NH), 256, 0, stream>>>(Qb, Kb, Vt, AO);
  k_gemm<1><<<dim3(D_MODEL/128, M/64, 1), 256, 0, stream>>>(
      AO, W0T, nullptr, nullptr, nullptr, nullptr, nullptr, out, 1.0f, D_MODEL, D_MODEL);
}

// Round 5
// 140.306 us; speedup vs baseline: 1.0032x; 1.0032x over previous
//
#include <hip/hip_runtime.h>

#define D_MODEL 1024
#define SEQ     2048
#define BATCH   2
#define NH      16

using u16 = unsigned short;
typedef __bf16 bf16x8 __attribute__((ext_vector_type(8)));
typedef float  f32x4  __attribute__((ext_vector_type(4)));

__device__ __forceinline__ u16 f2bf(float f){
  union { __bf16 h; u16 u; } v; v.h = (__bf16)f; return v.u;
}

__device__ __forceinline__ void gload_lds16(const void* g, void* l){
  __builtin_amdgcn_global_load_lds(
      (const __attribute__((address_space(1))) void*)g,
      (__attribute__((address_space(3))) void*)l, 16, 0, 0);
}

// ---------- kernel 1: fp32 -> bf16 (X) ----------
__global__ __launch_bounds__(256) void k_cvt(const float* __restrict__ in,
                                             u16* __restrict__ out, int n4){
  int i = blockIdx.x*256 + threadIdx.x;
  if (i >= n4) return;
  float4 v = ((const float4*)in)[i];
  ushort4 o; o.x=f2bf(v.x); o.y=f2bf(v.y); o.z=f2bf(v.z); o.w=f2bf(v.w);
  ((ushort4*)out)[i] = o;
}

// ---------- kernel 2: weight fp32[K][N] -> bf16 transposed [N][K] ----------
__global__ __launch_bounds__(256) void k_cvt_w_t(
    const float* __restrict__ wq, const float* __restrict__ wk,
    const float* __restrict__ wv, const float* __restrict__ w0,
    u16* __restrict__ oq, u16* __restrict__ ok,
    u16* __restrict__ ov, u16* __restrict__ o0){
  const float* W; u16* O;
  if      (blockIdx.z==0){W=wq;O=oq;}
  else if (blockIdx.z==1){W=wk;O=ok;}
  else if (blockIdx.z==2){W=wv;O=ov;}
  else               {W=w0;O=o0;}
  __shared__ float T[64][65];
  int t = threadIdx.x;
  int r0 = t>>4, cb = (t&15)*4;
  int kt = blockIdx.y*64, nt = blockIdx.x*64;
  #pragma unroll
  for (int j=0;j<4;++j){
    int r = r0 + j*16;
    float4 v = *(const float4*)(W + (size_t)(kt + r)*1024 + nt + cb);
    T[r][cb] = v.x; T[r][cb+1] = v.y; T[r][cb+2] = v.z; T[r][cb+3] = v.w;
  }
  __syncthreads();
  #pragma unroll
  for (int j=0;j<4;++j){
    int rn = r0 + j*16;
    ushort4 o;
    o.x = f2bf(T[cb  ][rn]); o.y = f2bf(T[cb+1][rn]);
    o.z = f2bf(T[cb+2][rn]); o.w = f2bf(T[cb+3][rn]);
    *(ushort4*)(O + (size_t)(nt + rn)*1024 + kt + cb) = o;
  }
}

// ---------- kernel 3: fused QKV GEMM  QKV[M,3072] = X[M,1024] @ WqkvT^T ----
// 128x128 tile, 2-phase dbuf. Q columns (bn<1024) get scaleQ in epilogue.
__global__ __launch_bounds__(256) void k_gemm_qkv(
    const u16* __restrict__ A, const u16* __restrict__ Bt,
    u16* __restrict__ Ob, float scaleQ)
{
  const int K = 1024, N = 3072;
  const int bm = blockIdx.y*128, bn = blockIdx.x*128;
  const float scl = (bn < 1024) ? scaleQ : 1.0f;
  const int lane = threadIdx.x & 63, w = threadIdx.x >> 6;
  const int hi = lane >> 4, c = lane & 15;
  const int wr = w >> 1, wc = w & 1;

  __shared__ u16 As[2][128*32];
  __shared__ u16 Bs[2][128*32];

  const int i0 = 2*w, i1 = 2*w+1;
  const int rA0 = i0*16 + (lane>>2), rA1 = i1*16 + (lane>>2);
  const int cA  = (lane&3)*8;
  const u16* aS0 = A  + (size_t)(bm + rA0)*K + cA;
  const u16* aS1 = A  + (size_t)(bm + rA1)*K + cA;
  const u16* bS0 = Bt + (size_t)(bn + rA0)*K + cA;
  const u16* bS1 = Bt + (size_t)(bn + rA1)*K + cA;

  auto stage = [&](int buf, int kk){
    gload_lds16(aS0 + kk, As[buf] + i0*512);
    gload_lds16(aS1 + kk, As[buf] + i1*512);
    gload_lds16(bS0 + kk, Bs[buf] + i0*512);
    gload_lds16(bS1 + kk, Bs[buf] + i1*512);
  };

  f32x4 acc[4][4];
  #pragma unroll
  for (int mi=0;mi<4;++mi)
    #pragma unroll
    for (int ni=0;ni<4;++ni) acc[mi][ni] = (f32x4){0.f,0.f,0.f,0.f};

  stage(0, 0);
  __syncthreads();
  int cur = 0;
  for (int kk = 0; kk < K; kk += 32){
    if (kk + 32 < K) stage(cur^1, kk + 32);
    const u16* as = As[cur];
    const u16* bs = Bs[cur];
    bf16x8 af[4], bfr[4];
    #pragma unroll
    for (int mi=0;mi<4;++mi)
      af[mi] = *(const bf16x8*)(as + (wr*64 + mi*16 + c)*32 + hi*8);
    #pragma unroll
    for (int ni=0;ni<4;++ni)
      bfr[ni] = *(const bf16x8*)(bs + (wc*64 + ni*16 + c)*32 + hi*8);
    #pragma unroll
    for (int mi=0;mi<4;++mi)
      #pragma unroll
      for (int ni=0;ni<4;++ni)
        acc[mi][ni] = __builtin_amdgcn_mfma_f32_16x16x32_bf16(af[mi], bfr[ni], acc[mi][ni], 0, 0, 0);
    __syncthreads();
    cur ^= 1;
  }
  #pragma unroll
  for (int mi=0;mi<4;++mi){
    #pragma unroll
    for (int ni=0;ni<4;++ni){
      int row = bm + wr*64 + mi*16 + hi*4;
      int col = bn + wc*64 + ni*16 + c;
      #pragma unroll
      for (int r=0;r<4;++r)
        Ob[(size_t)(row + r)*N + col] = f2bf(acc[mi][ni][r] * scl);
    }
  }
}

// ---------- kernel 6: out-proj GEMM  C[M,1024] = AO @ W0T^T (fp32 out) -----
// 64x128 tile for 2 blocks/CU.
__global__ __launch_bounds__(256) void k_gemm_out(
    const u16* __restrict__ A, const u16* __restrict__ Bt,
    float* __restrict__ OF)
{
  const int K = 1024, N = 1024;
  const int bm = blockIdx.y*64, bn = blockIdx.x*128;
  const int lane = threadIdx.x & 63, w = threadIdx.x >> 6;
  const int hi = lane >> 4, c = lane & 15;
  const int wr = w >> 1, wc = w & 1;

  __shared__ u16 As[2][64*32];
  __shared__ u16 Bs[2][128*32];

  const int i0 = 2*w, i1 = 2*w+1;
  const int cA = (lane&3)*8;
  const u16* aS  = A  + (size_t)(bm + w*16  + (lane>>2))*K + cA;
  const u16* bS0 = Bt + (size_t)(bn + i0*16 + (lane>>2))*K + cA;
  const u16* bS1 = Bt + (size_t)(bn + i1*16 + (lane>>2))*K + cA;

  auto stage = [&](int buf, int kk){
    gload_lds16(aS  + kk, As[buf] + w*512);
    gload_lds16(bS0 + kk, Bs[buf] + i0*512);
    gload_lds16(bS1 + kk, Bs[buf] + i1*512);
  };

  f32x4 acc[2][4];
  #pragma unroll
  for (int mi=0;mi<2;++mi)
    #pragma unroll
    for (int ni=0;ni<4;++ni) acc[mi][ni] = (f32x4){0.f,0.f,0.f,0.f};

  stage(0, 0);
  __syncthreads();
  int cur = 0;
  for (int kk = 0; kk < K; kk += 32){
    if (kk + 32 < K) stage(cur^1, kk + 32);
    const u16* as = As[cur];
    const u16* bs = Bs[cur];
    bf16x8 af[2], bfr[4];
    #pragma unroll
    for (int mi=0;mi<2;++mi)
      af[mi] = *(const bf16x8*)(as + (wr*32 + mi*16 + c)*32 + hi*8);
    #pragma unroll
    for (int ni=0;ni<4;++ni)
      bfr[ni] = *(const bf16x8*)(bs + (wc*64 + ni*16 + c)*32 + hi*8);
    #pragma unroll
    for (int mi=0;mi<2;++mi)
      #pragma unroll
      for (int ni=0;ni<4;++ni)
        acc[mi][ni] = __builtin_amdgcn_mfma_f32_16x16x32_bf16(af[mi], bfr[ni], acc[mi][ni], 0, 0, 0);
    __syncthreads();
    cur ^= 1;
  }
  #pragma unroll
  for (int mi=0;mi<2;++mi){
    #pragma unroll
    for (int ni=0;ni<4;++ni){
      int row = bm + wr*32 + mi*16 + hi*4;
      int col = bn + wc*64 + ni*16 + c;
      #pragma unroll
      for (int r=0;r<4;++r)
        OF[(size_t)(row + r)*N + col] = acc[mi][ni][r];
    }
  }
}

// ---------- kernel 4: V (QKV col 2048+) -> Vt [B*H][64][S] ----------
__global__ __launch_bounds__(256) void k_trans_v(const u16* __restrict__ QKV,
                                                 u16* __restrict__ Vt){
  int st = blockIdx.x, bh = blockIdx.y;
  int b = bh >> 4, h = bh & 15;
  __shared__ u16 T[64][80];
  int t = threadIdx.x;
  {
    int s = t >> 2, dc = (t & 3)*16;
    const u16* src = QKV + (size_t)(b*SEQ + st*64 + s)*3072 + 2048 + h*64 + dc;
    *(uint4*)&T[s][dc]   = *(const uint4*)(src);
    *(uint4*)&T[s][dc+8] = *(const uint4*)(src + 8);
  }
  __syncthreads();
  {
    int d = t >> 2, sc = (t & 3)*16;
    u16* dst = Vt + ((size_t)bh*64 + d)*SEQ + st*64 + sc;
    uint4 w0, w1;
    w0.x = (unsigned)T[sc+ 0][d] | ((unsigned)T[sc+ 1][d] << 16);
    w0.y = (unsigned)T[sc+ 2][d] | ((unsigned)T[sc+ 3][d] << 16);
    w0.z = (unsigned)T[sc+ 4][d] | ((unsigned)T[sc+ 5][d] << 16);
    w0.w = (unsigned)T[sc+ 6][d] | ((unsigned)T[sc+ 7][d] << 16);
    w1.x = (unsigned)T[sc+ 8][d] | ((unsigned)T[sc+ 9][d] << 16);
    w1.y = (unsigned)T[sc+10][d] | ((unsigned)T[sc+11][d] << 16);
    w1.z = (unsigned)T[sc+12][d] | ((unsigned)T[sc+13][d] << 16);
    w1.w = (unsigned)T[sc+14][d] | ((unsigned)T[sc+15][d] << 16);
    *(uint4*)(dst)     = w0;
    *(uint4*)(dst + 8) = w1;
  }
}

// ---------- kernel 5: attention ----------
// 8 waves = (4 q-groups) x (2 key-halves); 16 q x 32 keys per wave per tile.
// Key-halves merge additively in LDS epilogue (no max subtraction needed).
// Swizzle convention everywhere: byte_in_row ^= (row&7)<<4 applied to the
// FULL byte-within-row offset (R4 bug: chunk offsets added outside the XOR).
__global__ __launch_bounds__(512, 8) void k_attn(const u16* __restrict__ QKV,
                                                 const u16* __restrict__ Vt,
                                                 u16* __restrict__ AO)
{
  const int qt = blockIdx.x, bh = blockIdx.y;
  const int b = bh >> 4, h = bh & 15;
  const int lane = threadIdx.x & 63, w = threadIdx.x >> 6;
  const int qg = w >> 1, kh = w & 1;
  const int hi = lane >> 4, c = lane & 15;

  __shared__ u16 Ks[2][64*64];   // [key][dim] rows 128B, source-swizzled
  __shared__ u16 Vs[2][64*64];   // [dim][key] rows 128B, source-swizzled
  __shared__ u16 Ps[8][16*32];   // per-wave P: 16 rows x 64B, XOR (row>>2)<<4

  const size_t qrow = (size_t)(b*SEQ + qt*64 + qg*16 + c);
  const bf16x8 qf0 = *(const bf16x8*)(QKV + qrow*3072 + h*64 + hi*8);
  const bf16x8 qf1 = *(const bf16x8*)(QKV + qrow*3072 + h*64 + 32 + hi*8);

  bf16x8 ones;
  #pragma unroll
  for (int j=0;j<8;++j) ones[j] = (__bf16)1.0f;

  f32x4 acc_o[4];
  #pragma unroll
  for (int n=0;n<4;++n) acc_o[n] = (f32x4){0.f,0.f,0.f,0.f};
  f32x4 acc_l = (f32x4){0.f,0.f,0.f,0.f};

  // staging: wave w loads rows w*8..w*8+7 of the 64-row K tile and V tile
  const int r = w*8 + (lane>>3);
  const int sb = ((((lane&7)*16) ^ ((lane>>3)<<4)) >> 1);  // u16 units
  const u16* kSrc = QKV + (size_t)(b*SEQ + r)*3072 + 1024 + h*64 + sb;
  const u16* vSrc = Vt + ((size_t)bh*64 + r)*SEQ + sb;

  auto stage = [&](int buf){
    gload_lds16(kSrc, Ks[buf] + w*512);
    gload_lds16(vSrc, Vs[buf] + w*512);
    kSrc += (size_t)64*3072; vSrc += 64;
  };

  // hoisted LDS read/write bases; XOR applied to full byte-within-row offset
  const int swz = ((c&7)<<4);
  const char* kr0 = (const char*)&Ks[0][0] + (kh*32 + c)*128 + (( 0 + hi*16) ^ swz);
  const char* kr1 = (const char*)&Ks[0][0] + (kh*32 + c)*128 + ((64 + hi*16) ^ swz);
  const char* vr  = (const char*)&Vs[0][0] + c*128 + ((kh*64 + hi*16) ^ swz);
  char* pbase = (char*)&Ps[w][0];
  const int pwo = hi*256 + ((c*2) ^ (hi<<4));      // row=hi*4+i at +i*64
  const char* pr = (const char*)pbase + c*64 + ((hi*16) ^ (((c>>2)&3)<<4));

  auto body = [&](int buf){
    const int bo = buf*8192;
    f32x4 s0 = (f32x4){0.f,0.f,0.f,0.f};
    f32x4 s1 = (f32x4){0.f,0.f,0.f,0.f};
    {
      bf16x8 k00 = *(const bf16x8*)(kr0 + bo);
      bf16x8 k01 = *(const bf16x8*)(kr1 + bo);
      bf16x8 k10 = *(const bf16x8*)(kr0 + bo + 2048);
      bf16x8 k11 = *(const bf16x8*)(kr1 + bo + 2048);
      s0 = __builtin_amdgcn_mfma_f32_16x16x32_bf16(qf0, k00, s0, 0,0,0);
      s1 = __builtin_amdgcn_mfma_f32_16x16x32_bf16(qf0, k10, s1, 0,0,0);
      s0 = __builtin_amdgcn_mfma_f32_16x16x32_bf16(qf1, k01, s0, 0,0,0);
      s1 = __builtin_amdgcn_mfma_f32_16x16x32_bf16(qf1, k11, s1, 0,0,0);
    }
    #pragma unroll
    for (int i=0;i<4;++i){
      *(u16*)(pbase + pwo + i*64)        = f2bf(__builtin_amdgcn_exp2f(s0[i]));
      *(u16*)(pbase + (pwo^32) + i*64)   = f2bf(__builtin_amdgcn_exp2f(s1[i]));
    }
    bf16x8 pa = *(const bf16x8*)pr;
    acc_l = __builtin_amdgcn_mfma_f32_16x16x32_bf16(pa, ones, acc_l, 0,0,0);
    #pragma unroll
    for (int n=0;n<4;++n){
      bf16x8 vf = *(const bf16x8*)(vr + bo + n*2048);
      acc_o[n] = __builtin_amdgcn_mfma_f32_16x16x32_bf16(pa, vf, acc_o[n], 0,0,0);
    }
  };

  stage(0);
  __syncthreads();
  #pragma unroll 1
  for (int u = 0; u < SEQ/128; ++u){
    stage(1);
    body(0);
    __syncthreads();
    if (u != SEQ/128 - 1) stage(0);
    body(1);
    __syncthreads();
  }

  // merge key-halves: kh=1 writes partials to LDS, kh=0 adds + normalizes
  float* Of = (float*)&Ks[0][0];           // [qg][16][64] f32 = 16KB
  float* Lf = (float*)&Vs[0][0];           // [qg][16]
  if (kh == 1){
    #pragma unroll
    for (int n=0;n<4;++n)
      #pragma unroll
      for (int i=0;i<4;++i)
        Of[qg*1024 + (hi*4+i)*64 + n*16 + c] = acc_o[n][i];
    if (c == 0){
      #pragma unroll
      for (int i=0;i<4;++i) Lf[qg*16 + hi*4 + i] = acc_l[i];
    }
  }
  __syncthreads();
  if (kh == 0){
    float inv[4];
    #pragma unroll
    for (int i=0;i<4;++i)
      inv[i] = 1.0f / (acc_l[i] + Lf[qg*16 + hi*4 + i]);
    size_t obase = (size_t)(b*SEQ + qt*64 + qg*16 + hi*4)*D_MODEL + h*64;
    #pragma unroll
    for (int i=0;i<4;++i){
      #pragma unroll
      for (int n=0;n<4;++n){
        float o = acc_o[n][i] + Of[qg*1024 + (hi*4+i)*64 + n*16 + c];
        AO[obase + (size_t)i*D_MODEL + n*16 + c] = f2bf(o * inv[i]);
      }
    }
  }
}

extern "C" void kernel_launch(void* const* d_in, const int* in_sizes, int n_in,
                              void* d_out, int out_size, void* d_ws, size_t ws_size,
                              hipStream_t stream)
{
  const float* X  = (const float*)d_in[0];
  const float* Wq = (const float*)d_in[1];
  const float* Wk = (const float*)d_in[2];
  const float* Wv = (const float*)d_in[3];
  const float* W0 = (const float*)d_in[4];
  float* out = (float*)d_out;

  char* ws = (char*)d_ws;
  const size_t MB = 1024*1024;
  u16* Xb    = (u16*)(ws);           // 8 MB  [4096][1024]; reused as AO later
  u16* WqkvT = (u16*)(ws +  8*MB);   // 6 MB  [3072][1024] (Wq,Wk,Wv rows)
  u16* W0T   = (u16*)(ws + 14*MB);   // 2 MB
  u16* QKVb  = (u16*)(ws + 16*MB);   // 24 MB [4096][3072]
  u16* Vt    = (u16*)(ws + 40*MB);   // 8 MB  [B*H][64][SEQ]
  u16* AO    = Xb;                   // Xb dead after QKV GEMM

  const float scaleQ = 1.4426950408889634f / sqrtf((float)SEQ);
  const int M = BATCH*SEQ;

  k_cvt<<<dim3((M*D_MODEL/4 + 255)/256), 256, 0, stream>>>(X, Xb, M*D_MODEL/4);
  k_cvt_w_t<<<dim3(16,16,4), 256, 0, stream>>>(
      Wq, Wk, Wv, W0, WqkvT, WqkvT + 1024*1024, WqkvT + 2*1024*1024, W0T);
  k_gemm_qkv<<<dim3(3072/128, M/128), 256, 0, stream>>>(Xb, WqkvT, QKVb, scaleQ);
  k_trans_v<<<dim3(SEQ/64, BATCH*NH), 256, 0, stream>>>(QKVb, Vt);
  k_attn<<<dim3(SEQ/64, BATCH*NH), 512, 0, stream>>>(QKVb, Vt, AO);
  k_gemm_out<<<dim3(1024/128, M/64), 256, 0, stream>>>(AO, W0T, out);
}

// Round 6
// 135.218 us; speedup vs baseline: 1.0410x; 1.0376x over previous
//
#include <hip/hip_runtime.h>

#define D_MODEL 1024
#define SEQ     2048
#define BATCH   2
#define NH      16

using u16 = unsigned short;
typedef __bf16 bf16x8 __attribute__((ext_vector_type(8)));
typedef float  f32x4  __attribute__((ext_vector_type(4)));
typedef short  short4v __attribute__((ext_vector_type(4)));

__device__ __forceinline__ u16 f2bf(float f){
  union { __bf16 h; u16 u; } v; v.h = (__bf16)f; return v.u;
}

__device__ __forceinline__ void gload_lds16(const void* g, void* l){
  __builtin_amdgcn_global_load_lds(
      (const __attribute__((address_space(1))) void*)g,
      (__attribute__((address_space(3))) void*)l, 16, 0, 0);
}

// ---------- kernel 1: fp32 -> bf16 (X) ----------
__global__ __launch_bounds__(256) void k_cvt(const float* __restrict__ in,
                                             u16* __restrict__ out, int n4){
  int i = blockIdx.x*256 + threadIdx.x;
  if (i >= n4) return;
  float4 v = ((const float4*)in)[i];
  ushort4 o; o.x=f2bf(v.x); o.y=f2bf(v.y); o.z=f2bf(v.z); o.w=f2bf(v.w);
  ((ushort4*)out)[i] = o;
}

// ---------- kernel 2: weight fp32[K][N] -> bf16 transposed [N][K] ----------
__global__ __launch_bounds__(256) void k_cvt_w_t(
    const float* __restrict__ wq, const float* __restrict__ wk,
    const float* __restrict__ wv, const float* __restrict__ w0,
    u16* __restrict__ oq, u16* __restrict__ ok,
    u16* __restrict__ ov, u16* __restrict__ o0){
  const float* W; u16* O;
  if      (blockIdx.z==0){W=wq;O=oq;}
  else if (blockIdx.z==1){W=wk;O=ok;}
  else if (blockIdx.z==2){W=wv;O=ov;}
  else               {W=w0;O=o0;}
  __shared__ float T[64][65];
  int t = threadIdx.x;
  int r0 = t>>4, cb = (t&15)*4;
  int kt = blockIdx.y*64, nt = blockIdx.x*64;
  #pragma unroll
  for (int j=0;j<4;++j){
    int r = r0 + j*16;
    float4 v = *(const float4*)(W + (size_t)(kt + r)*1024 + nt + cb);
    T[r][cb] = v.x; T[r][cb+1] = v.y; T[r][cb+2] = v.z; T[r][cb+3] = v.w;
  }
  __syncthreads();
  #pragma unroll
  for (int j=0;j<4;++j){
    int rn = r0 + j*16;
    ushort4 o;
    o.x = f2bf(T[cb  ][rn]); o.y = f2bf(T[cb+1][rn]);
    o.z = f2bf(T[cb+2][rn]); o.w = f2bf(T[cb+3][rn]);
    *(ushort4*)(O + (size_t)(nt + rn)*1024 + kt + cb) = o;
  }
}

// ---------- kernel 3: fused QKV GEMM  QKV[M,3072] = X[M,1024] @ WqkvT^T ----
// 128x128 tile, 2-phase dbuf, XCD-swizzled blockIdx (nwg=768, %8==0).
__global__ __launch_bounds__(256) void k_gemm_qkv(
    const u16* __restrict__ A, const u16* __restrict__ Bt,
    u16* __restrict__ Ob, float scaleQ)
{
  const int K = 1024, N = 3072;
  const int nwg = gridDim.x * gridDim.y;
  const int f = blockIdx.y * gridDim.x + blockIdx.x;
  const int sw = (f & 7) * (nwg >> 3) + (f >> 3);
  const int bxs = sw % gridDim.x, bys = sw / gridDim.x;
  const int bm = bys*128, bn = bxs*128;
  const float scl = (bn < 1024) ? scaleQ : 1.0f;
  const int lane = threadIdx.x & 63, w = threadIdx.x >> 6;
  const int hi = lane >> 4, c = lane & 15;
  const int wr = w >> 1, wc = w & 1;

  __shared__ u16 As[2][128*32];
  __shared__ u16 Bs[2][128*32];

  const int i0 = 2*w, i1 = 2*w+1;
  const int rA0 = i0*16 + (lane>>2), rA1 = i1*16 + (lane>>2);
  const int cA  = (lane&3)*8;
  const u16* aS0 = A  + (size_t)(bm + rA0)*K + cA;
  const u16* aS1 = A  + (size_t)(bm + rA1)*K + cA;
  const u16* bS0 = Bt + (size_t)(bn + rA0)*K + cA;
  const u16* bS1 = Bt + (size_t)(bn + rA1)*K + cA;

  auto stage = [&](int buf, int kk){
    gload_lds16(aS0 + kk, As[buf] + i0*512);
    gload_lds16(aS1 + kk, As[buf] + i1*512);
    gload_lds16(bS0 + kk, Bs[buf] + i0*512);
    gload_lds16(bS1 + kk, Bs[buf] + i1*512);
  };

  f32x4 acc[4][4];
  #pragma unroll
  for (int mi=0;mi<4;++mi)
    #pragma unroll
    for (int ni=0;ni<4;++ni) acc[mi][ni] = (f32x4){0.f,0.f,0.f,0.f};

  stage(0, 0);
  __syncthreads();
  int cur = 0;
  for (int kk = 0; kk < K; kk += 32){
    if (kk + 32 < K) stage(cur^1, kk + 32);
    const u16* as = As[cur];
    const u16* bs = Bs[cur];
    bf16x8 af[4], bfr[4];
    #pragma unroll
    for (int mi=0;mi<4;++mi)
      af[mi] = *(const bf16x8*)(as + (wr*64 + mi*16 + c)*32 + hi*8);
    #pragma unroll
    for (int ni=0;ni<4;++ni)
      bfr[ni] = *(const bf16x8*)(bs + (wc*64 + ni*16 + c)*32 + hi*8);
    #pragma unroll
    for (int mi=0;mi<4;++mi)
      #pragma unroll
      for (int ni=0;ni<4;++ni)
        acc[mi][ni] = __builtin_amdgcn_mfma_f32_16x16x32_bf16(af[mi], bfr[ni], acc[mi][ni], 0, 0, 0);
    __syncthreads();
    cur ^= 1;
  }
  #pragma unroll
  for (int mi=0;mi<4;++mi){
    #pragma unroll
    for (int ni=0;ni<4;++ni){
      int row = bm + wr*64 + mi*16 + hi*4;
      int col = bn + wc*64 + ni*16 + c;
      #pragma unroll
      for (int r=0;r<4;++r)
        Ob[(size_t)(row + r)*N + col] = f2bf(acc[mi][ni][r] * scl);
    }
  }
}

// ---------- kernel 6: out-proj GEMM  C[M,1024] = AO @ W0T^T (fp32 out) -----
// 64x128 tile, XCD-swizzled (nwg=512, %8==0).
__global__ __launch_bounds__(256) void k_gemm_out(
    const u16* __restrict__ A, const u16* __restrict__ Bt,
    float* __restrict__ OF)
{
  const int K = 1024, N = 1024;
  const int nwg = gridDim.x * gridDim.y;
  const int f = blockIdx.y * gridDim.x + blockIdx.x;
  const int sw = (f & 7) * (nwg >> 3) + (f >> 3);
  const int bxs = sw % gridDim.x, bys = sw / gridDim.x;
  const int bm = bys*64, bn = bxs*128;
  const int lane = threadIdx.x & 63, w = threadIdx.x >> 6;
  const int hi = lane >> 4, c = lane & 15;
  const int wr = w >> 1, wc = w & 1;

  __shared__ u16 As[2][64*32];
  __shared__ u16 Bs[2][128*32];

  const int i0 = 2*w, i1 = 2*w+1;
  const int cA = (lane&3)*8;
  const u16* aS  = A  + (size_t)(bm + w*16  + (lane>>2))*K + cA;
  const u16* bS0 = Bt + (size_t)(bn + i0*16 + (lane>>2))*K + cA;
  const u16* bS1 = Bt + (size_t)(bn + i1*16 + (lane>>2))*K + cA;

  auto stage = [&](int buf, int kk){
    gload_lds16(aS  + kk, As[buf] + w*512);
    gload_lds16(bS0 + kk, Bs[buf] + i0*512);
    gload_lds16(bS1 + kk, Bs[buf] + i1*512);
  };

  f32x4 acc[2][4];
  #pragma unroll
  for (int mi=0;mi<2;++mi)
    #pragma unroll
    for (int ni=0;ni<4;++ni) acc[mi][ni] = (f32x4){0.f,0.f,0.f,0.f};

  stage(0, 0);
  __syncthreads();
  int cur = 0;
  for (int kk = 0; kk < K; kk += 32){
    if (kk + 32 < K) stage(cur^1, kk + 32);
    const u16* as = As[cur];
    const u16* bs = Bs[cur];
    bf16x8 af[2], bfr[4];
    #pragma unroll
    for (int mi=0;mi<2;++mi)
      af[mi] = *(const bf16x8*)(as + (wr*32 + mi*16 + c)*32 + hi*8);
    #pragma unroll
    for (int ni=0;ni<4;++ni)
      bfr[ni] = *(const bf16x8*)(bs + (wc*64 + ni*16 + c)*32 + hi*8);
    #pragma unroll
    for (int mi=0;mi<2;++mi)
      #pragma unroll
      for (int ni=0;ni<4;++ni)
        acc[mi][ni] = __builtin_amdgcn_mfma_f32_16x16x32_bf16(af[mi], bfr[ni], acc[mi][ni], 0, 0, 0);
    __syncthreads();
    cur ^= 1;
  }
  #pragma unroll
  for (int mi=0;mi<2;++mi){
    #pragma unroll
    for (int ni=0;ni<4;++ni){
      int row = bm + wr*32 + mi*16 + hi*4;
      int col = bn + wc*64 + ni*16 + c;
      #pragma unroll
      for (int r=0;r<4;++r)
        OF[(size_t)(row + r)*N + col] = acc[mi][ni][r];
    }
  }
}

// ---------- kernel 4: V (QKV col 2048+) -> Vt [B*H][64][S] ----------
__global__ __launch_bounds__(256) void k_trans_v(const u16* __restrict__ QKV,
                                                 u16* __restrict__ Vt){
  int st = blockIdx.x, bh = blockIdx.y;
  int b = bh >> 4, h = bh & 15;
  __shared__ u16 T[64][80];
  int t = threadIdx.x;
  {
    int s = t >> 2, dc = (t & 3)*16;
    const u16* src = QKV + (size_t)(b*SEQ + st*64 + s)*3072 + 2048 + h*64 + dc;
    *(uint4*)&T[s][dc]   = *(const uint4*)(src);
    *(uint4*)&T[s][dc+8] = *(const uint4*)(src + 8);
  }
  __syncthreads();
  {
    int d = t >> 2, sc = (t & 3)*16;
    u16* dst = Vt + ((size_t)bh*64 + d)*SEQ + st*64 + sc;
    uint4 w0, w1;
    w0.x = (unsigned)T[sc+ 0][d] | ((unsigned)T[sc+ 1][d] << 16);
    w0.y = (unsigned)T[sc+ 2][d] | ((unsigned)T[sc+ 3][d] << 16);
    w0.z = (unsigned)T[sc+ 4][d] | ((unsigned)T[sc+ 5][d] << 16);
    w0.w = (unsigned)T[sc+ 6][d] | ((unsigned)T[sc+ 7][d] << 16);
    w1.x = (unsigned)T[sc+ 8][d] | ((unsigned)T[sc+ 9][d] << 16);
    w1.y = (unsigned)T[sc+10][d] | ((unsigned)T[sc+11][d] << 16);
    w1.z = (unsigned)T[sc+12][d] | ((unsigned)T[sc+13][d] << 16);
    w1.w = (unsigned)T[sc+14][d] | ((unsigned)T[sc+15][d] << 16);
    *(uint4*)(dst)     = w0;
    *(uint4*)(dst + 8) = w1;
  }
}

// ---------- kernel 5: attention ----------
// 8 waves = (4 q-groups) x (2 key-halves); 16 q x 32 keys per wave per tile.
// SWAPPED QK^T: s = mfma(K_frag, Q_frag) -> C[row=key][col=q]; lane (c,hi)
// holds P[q=c][keys hi*4+i], which IS the A-fragment of 16x16x16 MFMA.
// exp2 + pack in-register, PV via K=16 MFMAs -> NO LDS P-bounce at all.
// lsum via ones-B MFMA. Key-halves merge additively in LDS epilogue.
__global__ __launch_bounds__(512, 8) void k_attn(const u16* __restrict__ QKV,
                                                 const u16* __restrict__ Vt,
                                                 u16* __restrict__ AO)
{
  const int qt = blockIdx.x, bh = blockIdx.y;
  const int b = bh >> 4, h = bh & 15;
  const int lane = threadIdx.x & 63, w = threadIdx.x >> 6;
  const int qg = w >> 1, kh = w & 1;
  const int hi = lane >> 4, c = lane & 15;

  __shared__ u16 Ks[2][64*64];   // [key][dim] rows 128B, source-swizzled
  __shared__ u16 Vs[2][64*64];   // [dim][key] rows 128B, source-swizzled

  const size_t qrow = (size_t)(b*SEQ + qt*64 + qg*16 + c);
  const bf16x8 qf0 = *(const bf16x8*)(QKV + qrow*3072 + h*64 + hi*8);
  const bf16x8 qf1 = *(const bf16x8*)(QKV + qrow*3072 + h*64 + 32 + hi*8);

  const short4v ones4 = {(short)0x3F80,(short)0x3F80,(short)0x3F80,(short)0x3F80};

  f32x4 acc_o[4];
  #pragma unroll
  for (int n=0;n<4;++n) acc_o[n] = (f32x4){0.f,0.f,0.f,0.f};
  f32x4 acc_l = (f32x4){0.f,0.f,0.f,0.f};

  // staging: wave w loads rows w*8..w*8+7 of the 64-row K tile and V tile
  const int r = w*8 + (lane>>3);
  const int sb = ((((lane&7)*16) ^ ((lane>>3)<<4)) >> 1);  // u16 units
  const u16* kSrc = QKV + (size_t)(b*SEQ + r)*3072 + 1024 + h*64 + sb;
  const u16* vSrc = Vt + ((size_t)bh*64 + r)*SEQ + sb;

  auto stage = [&](int buf){
    gload_lds16(kSrc, Ks[buf] + w*512);
    gload_lds16(vSrc, Vs[buf] + w*512);
    kSrc += (size_t)64*3072; vSrc += 64;
  };

  // hoisted LDS read bases; XOR applied to full byte-within-row offset
  const int swz = ((c&7)<<4);
  const char* kr0 = (const char*)&Ks[0][0] + (kh*32 + c)*128 + (( 0 + hi*16) ^ swz);
  const char* kr1 = (const char*)&Ks[0][0] + (kh*32 + c)*128 + ((64 + hi*16) ^ swz);
  // V as B-frag of 16x16x16: row = n*16+c (dim), keys (kh*32 + t*16 + hi*4..+3)
  const char* vr0 = (const char*)&Vs[0][0] + c*128 + ((kh*64 +      hi*8) ^ swz);
  const char* vr1 = (const char*)&Vs[0][0] + c*128 + ((kh*64 + 32 + hi*8) ^ swz);

  auto body = [&](int buf){
    const int bo = buf*8192;
    f32x4 s0 = (f32x4){0.f,0.f,0.f,0.f};
    f32x4 s1 = (f32x4){0.f,0.f,0.f,0.f};
    bf16x8 k00 = *(const bf16x8*)(kr0 + bo);
    bf16x8 k01 = *(const bf16x8*)(kr1 + bo);
    bf16x8 k10 = *(const bf16x8*)(kr0 + bo + 2048);
    bf16x8 k11 = *(const bf16x8*)(kr1 + bo + 2048);
    __builtin_amdgcn_s_setprio(1);
    s0 = __builtin_amdgcn_mfma_f32_16x16x32_bf16(k00, qf0, s0, 0,0,0);
    s1 = __builtin_amdgcn_mfma_f32_16x16x32_bf16(k10, qf0, s1, 0,0,0);
    s0 = __builtin_amdgcn_mfma_f32_16x16x32_bf16(k01, qf1, s0, 0,0,0);
    s1 = __builtin_amdgcn_mfma_f32_16x16x32_bf16(k11, qf1, s1, 0,0,0);
    __builtin_amdgcn_s_setprio(0);

    // exp2 + pack into PV A-fragments (lane-local, no cross-lane movement)
    short4v a0, a1;
    #pragma unroll
    for (int i=0;i<4;++i){
      a0[i] = (short)f2bf(__builtin_amdgcn_exp2f(s0[i]));
      a1[i] = (short)f2bf(__builtin_amdgcn_exp2f(s1[i]));
    }

    __builtin_amdgcn_s_setprio(1);
    acc_l = __builtin_amdgcn_mfma_f32_16x16x16bf16_1k(a0, ones4, acc_l, 0,0,0);
    acc_l = __builtin_amdgcn_mfma_f32_16x16x16bf16_1k(a1, ones4, acc_l, 0,0,0);
    #pragma unroll
    for (int n=0;n<4;++n){
      short4v v0 = *(const short4v*)(vr0 + bo + n*2048);
      short4v v1 = *(const short4v*)(vr1 + bo + n*2048);
      acc_o[n] = __builtin_amdgcn_mfma_f32_16x16x16bf16_1k(a0, v0, acc_o[n], 0,0,0);
      acc_o[n] = __builtin_amdgcn_mfma_f32_16x16x16bf16_1k(a1, v1, acc_o[n], 0,0,0);
    }
    __builtin_amdgcn_s_setprio(0);
  };

  stage(0);
  __syncthreads();
  #pragma unroll 1
  for (int u = 0; u < SEQ/128; ++u){
    stage(1);
    body(0);
    __syncthreads();
    if (u != SEQ/128 - 1) stage(0);
    body(1);
    __syncthreads();
  }

  // merge key-halves: kh=1 writes partials to LDS, kh=0 adds + normalizes
  float* Of = (float*)&Ks[0][0];           // [qg][16][64] f32 = 16KB
  float* Lf = (float*)&Vs[0][0];           // [qg][16]
  if (kh == 1){
    #pragma unroll
    for (int n=0;n<4;++n)
      #pragma unroll
      for (int i=0;i<4;++i)
        Of[qg*1024 + (hi*4+i)*64 + n*16 + c] = acc_o[n][i];
    if (c == 0){
      #pragma unroll
      for (int i=0;i<4;++i) Lf[qg*16 + hi*4 + i] = acc_l[i];
    }
  }
  __syncthreads();
  if (kh == 0){
    float inv[4];
    #pragma unroll
    for (int i=0;i<4;++i)
      inv[i] = 1.0f / (acc_l[i] + Lf[qg*16 + hi*4 + i]);
    size_t obase = (size_t)(b*SEQ + qt*64 + qg*16 + hi*4)*D_MODEL + h*64;
    #pragma unroll
    for (int i=0;i<4;++i){
      #pragma unroll
      for (int n=0;n<4;++n){
        float o = acc_o[n][i] + Of[qg*1024 + (hi*4+i)*64 + n*16 + c];
        AO[obase + (size_t)i*D_MODEL + n*16 + c] = f2bf(o * inv[i]);
      }
    }
  }
}

extern "C" void kernel_launch(void* const* d_in, const int* in_sizes, int n_in,
                              void* d_out, int out_size, void* d_ws, size_t ws_size,
                              hipStream_t stream)
{
  const float* X  = (const float*)d_in[0];
  const float* Wq = (const float*)d_in[1];
  const float* Wk = (const float*)d_in[2];
  const float* Wv = (const float*)d_in[3];
  const float* W0 = (const float*)d_in[4];
  float* out = (float*)d_out;

  char* ws = (char*)d_ws;
  const size_t MB = 1024*1024;
  u16* Xb    = (u16*)(ws);           // 8 MB  [4096][1024]; reused as AO later
  u16* WqkvT = (u16*)(ws +  8*MB);   // 6 MB  [3072][1024] (Wq,Wk,Wv rows)
  u16* W0T   = (u16*)(ws + 14*MB);   // 2 MB
  u16* QKVb  = (u16*)(ws + 16*MB);   // 24 MB [4096][3072]
  u16* Vt    = (u16*)(ws + 40*MB);   // 8 MB  [B*H][64][SEQ]
  u16* AO    = Xb;                   // Xb dead after QKV GEMM

  const float scaleQ = 1.4426950408889634f / sqrtf((float)SEQ);
  const int M = BATCH*SEQ;

  k_cvt<<<dim3((M*D_MODEL/4 + 255)/256), 256, 0, stream>>>(X, Xb, M*D_MODEL/4);
  k_cvt_w_t<<<dim3(16,16,4), 256, 0, stream>>>(
      Wq, Wk, Wv, W0, WqkvT, WqkvT + 1024*1024, WqkvT + 2*1024*1024, W0T);
  k_gemm_qkv<<<dim3(3072/128, M/128), 256, 0, stream>>>(Xb, WqkvT, QKVb, scaleQ);
  k_trans_v<<<dim3(SEQ/64, BATCH*NH), 256, 0, stream>>>(QKVb, Vt);
  k_attn<<<dim3(SEQ/64, BATCH*NH), 512, 0, stream>>>(QKVb, Vt, AO);
  k_gemm_out<<<dim3(1024/128, M/64), 256, 0, stream>>>(AO, W0T, out);
}

// Round 7
// 132.849 us; speedup vs baseline: 1.0595x; 1.0178x over previous
//
#include <hip/hip_runtime.h>

#define D_MODEL 1024
#define SEQ     2048
#define BATCH   2
#define NH      16

using u16 = unsigned short;
typedef __bf16 bf16x8 __attribute__((ext_vector_type(8)));
typedef float  f32x4  __attribute__((ext_vector_type(4)));
typedef short  short4v __attribute__((ext_vector_type(4)));
typedef short  short8v __attribute__((ext_vector_type(8)));

__device__ __forceinline__ u16 f2bf(float f){
  union { __bf16 h; u16 u; } v; v.h = (__bf16)f; return v.u;
}

__device__ __forceinline__ void gload_lds16(const void* g, void* l){
  __builtin_amdgcn_global_load_lds(
      (const __attribute__((address_space(1))) void*)g,
      (__attribute__((address_space(3))) void*)l, 16, 0, 0);
}

// ---------- kernel 1: fp32 -> bf16 (X) ----------
__global__ __launch_bounds__(256) void k_cvt(const float* __restrict__ in,
                                             u16* __restrict__ out, int n4){
  int i = blockIdx.x*256 + threadIdx.x;
  if (i >= n4) return;
  float4 v = ((const float4*)in)[i];
  ushort4 o; o.x=f2bf(v.x); o.y=f2bf(v.y); o.z=f2bf(v.z); o.w=f2bf(v.w);
  ((ushort4*)out)[i] = o;
}

// ---------- kernel 2: weight fp32[K][N] -> bf16 transposed [N][K] ----------
__global__ __launch_bounds__(256) void k_cvt_w_t(
    const float* __restrict__ wq, const float* __restrict__ wk,
    const float* __restrict__ wv, const float* __restrict__ w0,
    u16* __restrict__ oq, u16* __restrict__ ok,
    u16* __restrict__ ov, u16* __restrict__ o0){
  const float* W; u16* O;
  if      (blockIdx.z==0){W=wq;O=oq;}
  else if (blockIdx.z==1){W=wk;O=ok;}
  else if (blockIdx.z==2){W=wv;O=ov;}
  else               {W=w0;O=o0;}
  __shared__ float T[64][65];
  int t = threadIdx.x;
  int r0 = t>>4, cb = (t&15)*4;
  int kt = blockIdx.y*64, nt = blockIdx.x*64;
  #pragma unroll
  for (int j=0;j<4;++j){
    int r = r0 + j*16;
    float4 v = *(const float4*)(W + (size_t)(kt + r)*1024 + nt + cb);
    T[r][cb] = v.x; T[r][cb+1] = v.y; T[r][cb+2] = v.z; T[r][cb+3] = v.w;
  }
  __syncthreads();
  #pragma unroll
  for (int j=0;j<4;++j){
    int rn = r0 + j*16;
    ushort4 o;
    o.x = f2bf(T[cb  ][rn]); o.y = f2bf(T[cb+1][rn]);
    o.z = f2bf(T[cb+2][rn]); o.w = f2bf(T[cb+3][rn]);
    *(ushort4*)(O + (size_t)(nt + rn)*1024 + kt + cb) = o;
  }
}

// ---------- kernel 3: fused QKV GEMM  QKV[M,3072] = X[M,1024] @ WqkvT^T ----
// 128x128 tile, 2-phase dbuf, XCD-swizzled blockIdx (nwg=768, %8==0).
__global__ __launch_bounds__(256) void k_gemm_qkv(
    const u16* __restrict__ A, const u16* __restrict__ Bt,
    u16* __restrict__ Ob, float scaleQ)
{
  const int K = 1024, N = 3072;
  const int nwg = gridDim.x * gridDim.y;
  const int f = blockIdx.y * gridDim.x + blockIdx.x;
  const int sw = (f & 7) * (nwg >> 3) + (f >> 3);
  const int bxs = sw % gridDim.x, bys = sw / gridDim.x;
  const int bm = bys*128, bn = bxs*128;
  const float scl = (bn < 1024) ? scaleQ : 1.0f;
  const int lane = threadIdx.x & 63, w = threadIdx.x >> 6;
  const int hi = lane >> 4, c = lane & 15;
  const int wr = w >> 1, wc = w & 1;

  __shared__ u16 As[2][128*32];
  __shared__ u16 Bs[2][128*32];

  const int i0 = 2*w, i1 = 2*w+1;
  const int rA0 = i0*16 + (lane>>2), rA1 = i1*16 + (lane>>2);
  const int cA  = (lane&3)*8;
  const u16* aS0 = A  + (size_t)(bm + rA0)*K + cA;
  const u16* aS1 = A  + (size_t)(bm + rA1)*K + cA;
  const u16* bS0 = Bt + (size_t)(bn + rA0)*K + cA;
  const u16* bS1 = Bt + (size_t)(bn + rA1)*K + cA;

  auto stage = [&](int buf, int kk){
    gload_lds16(aS0 + kk, As[buf] + i0*512);
    gload_lds16(aS1 + kk, As[buf] + i1*512);
    gload_lds16(bS0 + kk, Bs[buf] + i0*512);
    gload_lds16(bS1 + kk, Bs[buf] + i1*512);
  };

  f32x4 acc[4][4];
  #pragma unroll
  for (int mi=0;mi<4;++mi)
    #pragma unroll
    for (int ni=0;ni<4;++ni) acc[mi][ni] = (f32x4){0.f,0.f,0.f,0.f};

  stage(0, 0);
  __syncthreads();
  int cur = 0;
  for (int kk = 0; kk < K; kk += 32){
    if (kk + 32 < K) stage(cur^1, kk + 32);
    const u16* as = As[cur];
    const u16* bs = Bs[cur];
    bf16x8 af[4], bfr[4];
    #pragma unroll
    for (int mi=0;mi<4;++mi)
      af[mi] = *(const bf16x8*)(as + (wr*64 + mi*16 + c)*32 + hi*8);
    #pragma unroll
    for (int ni=0;ni<4;++ni)
      bfr[ni] = *(const bf16x8*)(bs + (wc*64 + ni*16 + c)*32 + hi*8);
    #pragma unroll
    for (int mi=0;mi<4;++mi)
      #pragma unroll
      for (int ni=0;ni<4;++ni)
        acc[mi][ni] = __builtin_amdgcn_mfma_f32_16x16x32_bf16(af[mi], bfr[ni], acc[mi][ni], 0, 0, 0);
    __syncthreads();
    cur ^= 1;
  }
  #pragma unroll
  for (int mi=0;mi<4;++mi){
    #pragma unroll
    for (int ni=0;ni<4;++ni){
      int row = bm + wr*64 + mi*16 + hi*4;
      int col = bn + wc*64 + ni*16 + c;
      #pragma unroll
      for (int r=0;r<4;++r)
        Ob[(size_t)(row + r)*N + col] = f2bf(acc[mi][ni][r] * scl);
    }
  }
}

// ---------- kernel 6: out-proj GEMM  C[M,1024] = AO @ W0T^T (fp32 out) -----
// 64x128 tile, XCD-swizzled (nwg=512, %8==0).
__global__ __launch_bounds__(256) void k_gemm_out(
    const u16* __restrict__ A, const u16* __restrict__ Bt,
    float* __restrict__ OF)
{
  const int K = 1024, N = 1024;
  const int nwg = gridDim.x * gridDim.y;
  const int f = blockIdx.y * gridDim.x + blockIdx.x;
  const int sw = (f & 7) * (nwg >> 3) + (f >> 3);
  const int bxs = sw % gridDim.x, bys = sw / gridDim.x;
  const int bm = bys*64, bn = bxs*128;
  const int lane = threadIdx.x & 63, w = threadIdx.x >> 6;
  const int hi = lane >> 4, c = lane & 15;
  const int wr = w >> 1, wc = w & 1;

  __shared__ u16 As[2][64*32];
  __shared__ u16 Bs[2][128*32];

  const int i0 = 2*w, i1 = 2*w+1;
  const int cA = (lane&3)*8;
  const u16* aS  = A  + (size_t)(bm + w*16  + (lane>>2))*K + cA;
  const u16* bS0 = Bt + (size_t)(bn + i0*16 + (lane>>2))*K + cA;
  const u16* bS1 = Bt + (size_t)(bn + i1*16 + (lane>>2))*K + cA;

  auto stage = [&](int buf, int kk){
    gload_lds16(aS  + kk, As[buf] + w*512);
    gload_lds16(bS0 + kk, Bs[buf] + i0*512);
    gload_lds16(bS1 + kk, Bs[buf] + i1*512);
  };

  f32x4 acc[2][4];
  #pragma unroll
  for (int mi=0;mi<2;++mi)
    #pragma unroll
    for (int ni=0;ni<4;++ni) acc[mi][ni] = (f32x4){0.f,0.f,0.f,0.f};

  stage(0, 0);
  __syncthreads();
  int cur = 0;
  for (int kk = 0; kk < K; kk += 32){
    if (kk + 32 < K) stage(cur^1, kk + 32);
    const u16* as = As[cur];
    const u16* bs = Bs[cur];
    bf16x8 af[2], bfr[4];
    #pragma unroll
    for (int mi=0;mi<2;++mi)
      af[mi] = *(const bf16x8*)(as + (wr*32 + mi*16 + c)*32 + hi*8);
    #pragma unroll
    for (int ni=0;ni<4;++ni)
      bfr[ni] = *(const bf16x8*)(bs + (wc*64 + ni*16 + c)*32 + hi*8);
    #pragma unroll
    for (int mi=0;mi<2;++mi)
      #pragma unroll
      for (int ni=0;ni<4;++ni)
        acc[mi][ni] = __builtin_amdgcn_mfma_f32_16x16x32_bf16(af[mi], bfr[ni], acc[mi][ni], 0, 0, 0);
    __syncthreads();
    cur ^= 1;
  }
  #pragma unroll
  for (int mi=0;mi<2;++mi){
    #pragma unroll
    for (int ni=0;ni<4;++ni){
      int row = bm + wr*32 + mi*16 + hi*4;
      int col = bn + wc*64 + ni*16 + c;
      #pragma unroll
      for (int r=0;r<4;++r)
        OF[(size_t)(row + r)*N + col] = acc[mi][ni][r];
    }
  }
}

// ---------- kernel 4: V (QKV col 2048+) -> Vt [B*H][64][S-permuted] --------
// Key order inside each 64-key tile is permuted: pos = [kh hi1 hi0 t j1 j0]
// for key s = [kh t hi1 hi0 j1 j0], so the attention PV B-fragment
// (keys {t*16+hi*4+j, t=0,1}) is ONE contiguous 16B block per lane ->
// b128 V-reads with the same conflict-free o-structure as K-reads.
__global__ __launch_bounds__(256) void k_trans_v(const u16* __restrict__ QKV,
                                                 u16* __restrict__ Vt){
  int st = blockIdx.x, bh = blockIdx.y;
  int b = bh >> 4, h = bh & 15;
  __shared__ u16 T[64][80];
  int t = threadIdx.x;
  {
    int s = t >> 2, dc = (t & 3)*16;
    const u16* src = QKV + (size_t)(b*SEQ + st*64 + s)*3072 + 2048 + h*64 + dc;
    *(uint4*)&T[s][dc]   = *(const uint4*)(src);
    *(uint4*)&T[s][dc+8] = *(const uint4*)(src + 8);
  }
  __syncthreads();
  {
    int d = t >> 2, sc = (t & 3)*16;
    u16* dst = Vt + ((size_t)bh*64 + d)*SEQ + st*64 + sc;
    u16 vals[16];
    #pragma unroll
    for (int x=0;x<16;++x){
      int p = sc + x;
      int s = (p & 0x23) | ((p & 0x04) << 2) | ((p & 0x18) >> 1);
      vals[x] = T[s][d];
    }
    uint4 w0, w1;
    w0.x = (unsigned)vals[ 0] | ((unsigned)vals[ 1] << 16);
    w0.y = (unsigned)vals[ 2] | ((unsigned)vals[ 3] << 16);
    w0.z = (unsigned)vals[ 4] | ((unsigned)vals[ 5] << 16);
    w0.w = (unsigned)vals[ 6] | ((unsigned)vals[ 7] << 16);
    w1.x = (unsigned)vals[ 8] | ((unsigned)vals[ 9] << 16);
    w1.y = (unsigned)vals[10] | ((unsigned)vals[11] << 16);
    w1.z = (unsigned)vals[12] | ((unsigned)vals[13] << 16);
    w1.w = (unsigned)vals[14] | ((unsigned)vals[15] << 16);
    *(uint4*)(dst)     = w0;
    *(uint4*)(dst + 8) = w1;
  }
}

// ---------- kernel 5: attention ----------
// 8 waves = (4 q-groups) x (2 key-halves); 16 q x 32 keys per wave per tile.
// SWAPPED QK^T: s = mfma(K,Q) -> lane (c,hi) holds P[q=c][key=t*16+hi*4+i]
// = the PV A-fragment. exp2+pack in-register; PV via K=16 MFMAs; V keys
// pre-permuted (k_trans_v) so each lane's PV B-frag is one b128 read.
__global__ __launch_bounds__(512, 8) void k_attn(const u16* __restrict__ QKV,
                                                 const u16* __restrict__ Vt,
                                                 u16* __restrict__ AO)
{
  const int qt = blockIdx.x, bh = blockIdx.y;
  const int b = bh >> 4, h = bh & 15;
  const int lane = threadIdx.x & 63, w = threadIdx.x >> 6;
  const int qg = w >> 1, kh = w & 1;
  const int hi = lane >> 4, c = lane & 15;

  __shared__ u16 Ks[2][64*64];   // [key][dim] rows 128B, source-swizzled
  __shared__ u16 Vs[2][64*64];   // [dim][key'] rows 128B, source-swizzled

  const size_t qrow = (size_t)(b*SEQ + qt*64 + qg*16 + c);
  const bf16x8 qf0 = *(const bf16x8*)(QKV + qrow*3072 + h*64 + hi*8);
  const bf16x8 qf1 = *(const bf16x8*)(QKV + qrow*3072 + h*64 + 32 + hi*8);

  const short4v ones4 = {(short)0x3F80,(short)0x3F80,(short)0x3F80,(short)0x3F80};

  f32x4 acc_o[4];
  #pragma unroll
  for (int n=0;n<4;++n) acc_o[n] = (f32x4){0.f,0.f,0.f,0.f};
  f32x4 acc_l = (f32x4){0.f,0.f,0.f,0.f};

  // staging: wave w loads rows w*8..w*8+7 of the 64-row K tile and V tile
  const int r = w*8 + (lane>>3);
  const int sb = ((((lane&7)*16) ^ ((lane>>3)<<4)) >> 1);  // u16 units
  const u16* kSrc = QKV + (size_t)(b*SEQ + r)*3072 + 1024 + h*64 + sb;
  const u16* vSrc = Vt + ((size_t)bh*64 + r)*SEQ + sb;

  auto stage = [&](int buf){
    gload_lds16(kSrc, Ks[buf] + w*512);
    gload_lds16(vSrc, Vs[buf] + w*512);
    kSrc += (size_t)64*3072; vSrc += 64;
  };

  // hoisted LDS read bases; XOR applied to full byte-within-row offset
  const int swz = ((c&7)<<4);
  const char* kr0 = (const char*)&Ks[0][0] + (kh*32 + c)*128 + (( 0 + hi*16) ^ swz);
  const char* kr1 = (const char*)&Ks[0][0] + (kh*32 + c)*128 + ((64 + hi*16) ^ swz);
  // V B-frag: one b128 per n: row=c, 16B block at (kh*64 + hi*16)^swz;
  // block = [t0:j0..3 | t1:j0..3] thanks to the key permutation.
  const char* vr  = (const char*)&Vs[0][0] + c*128 + ((kh*64 + hi*16) ^ swz);

  auto body = [&](int buf){
    const int bo = buf*8192;
    f32x4 s0 = (f32x4){0.f,0.f,0.f,0.f};
    f32x4 s1 = (f32x4){0.f,0.f,0.f,0.f};
    bf16x8 k00 = *(const bf16x8*)(kr0 + bo);
    bf16x8 k01 = *(const bf16x8*)(kr1 + bo);
    bf16x8 k10 = *(const bf16x8*)(kr0 + bo + 2048);
    bf16x8 k11 = *(const bf16x8*)(kr1 + bo + 2048);
    __builtin_amdgcn_s_setprio(1);
    s0 = __builtin_amdgcn_mfma_f32_16x16x32_bf16(k00, qf0, s0, 0,0,0);
    s1 = __builtin_amdgcn_mfma_f32_16x16x32_bf16(k10, qf0, s1, 0,0,0);
    s0 = __builtin_amdgcn_mfma_f32_16x16x32_bf16(k01, qf1, s0, 0,0,0);
    s1 = __builtin_amdgcn_mfma_f32_16x16x32_bf16(k11, qf1, s1, 0,0,0);
    __builtin_amdgcn_s_setprio(0);

    // exp2 + pack into PV A-fragments (lane-local, no cross-lane movement)
    short4v a0, a1;
    #pragma unroll
    for (int i=0;i<4;++i){
      a0[i] = (short)f2bf(__builtin_amdgcn_exp2f(s0[i]));
      a1[i] = (short)f2bf(__builtin_amdgcn_exp2f(s1[i]));
    }

    __builtin_amdgcn_s_setprio(1);
    acc_l = __builtin_amdgcn_mfma_f32_16x16x16bf16_1k(a0, ones4, acc_l, 0,0,0);
    acc_l = __builtin_amdgcn_mfma_f32_16x16x16bf16_1k(a1, ones4, acc_l, 0,0,0);
    #pragma unroll
    for (int n=0;n<4;++n){
      short8v vv = *(const short8v*)(vr + bo + n*2048);
      short4v v0 = __builtin_shufflevector(vv, vv, 0,1,2,3);
      short4v v1 = __builtin_shufflevector(vv, vv, 4,5,6,7);
      acc_o[n] = __builtin_amdgcn_mfma_f32_16x16x16bf16_1k(a0, v0, acc_o[n], 0,0,0);
      acc_o[n] = __builtin_amdgcn_mfma_f32_16x16x16bf16_1k(a1, v1, acc_o[n], 0,0,0);
    }
    __builtin_amdgcn_s_setprio(0);
  };

  stage(0);
  __syncthreads();
  #pragma unroll 1
  for (int u = 0; u < SEQ/128; ++u){
    stage(1);
    body(0);
    __syncthreads();
    if (u != SEQ/128 - 1) stage(0);
    body(1);
    __syncthreads();
  }

  // merge key-halves: kh=1 writes partials to LDS, kh=0 adds + normalizes
  float* Of = (float*)&Ks[0][0];           // [qg][16][64] f32 = 16KB
  float* Lf = (float*)&Vs[0][0];           // [qg][16]
  if (kh == 1){
    #pragma unroll
    for (int n=0;n<4;++n)
      #pragma unroll
      for (int i=0;i<4;++i)
        Of[qg*1024 + (hi*4+i)*64 + n*16 + c] = acc_o[n][i];
    if (c == 0){
      #pragma unroll
      for (int i=0;i<4;++i) Lf[qg*16 + hi*4 + i] = acc_l[i];
    }
  }
  __syncthreads();
  if (kh == 0){
    float inv[4];
    #pragma unroll
    for (int i=0;i<4;++i)
      inv[i] = 1.0f / (acc_l[i] + Lf[qg*16 + hi*4 + i]);
    size_t obase = (size_t)(b*SEQ + qt*64 + qg*16 + hi*4)*D_MODEL + h*64;
    #pragma unroll
    for (int i=0;i<4;++i){
      #pragma unroll
      for (int n=0;n<4;++n){
        float o = acc_o[n][i] + Of[qg*1024 + (hi*4+i)*64 + n*16 + c];
        AO[obase + (size_t)i*D_MODEL + n*16 + c] = f2bf(o * inv[i]);
      }
    }
  }
}

extern "C" void kernel_launch(void* const* d_in, const int* in_sizes, int n_in,
                              void* d_out, int out_size, void* d_ws, size_t ws_size,
                              hipStream_t stream)
{
  const float* X  = (const float*)d_in[0];
  const float* Wq = (const float*)d_in[1];
  const float* Wk = (const float*)d_in[2];
  const float* Wv = (const float*)d_in[3];
  const float* W0 = (const float*)d_in[4];
  float* out = (float*)d_out;

  char* ws = (char*)d_ws;
  const size_t MB = 1024*1024;
  u16* Xb    = (u16*)(ws);           // 8 MB  [4096][1024]; reused as AO later
  u16* WqkvT = (u16*)(ws +  8*MB);   // 6 MB  [3072][1024] (Wq,Wk,Wv rows)
  u16* W0T   = (u16*)(ws + 14*MB);   // 2 MB
  u16* QKVb  = (u16*)(ws + 16*MB);   // 24 MB [4096][3072]
  u16* Vt    = (u16*)(ws + 40*MB);   // 8 MB  [B*H][64][SEQ] (keys permuted)
  u16* AO    = Xb;                   // Xb dead after QKV GEMM

  const float scaleQ = 1.4426950408889634f / sqrtf((float)SEQ);
  const int M = BATCH*SEQ;

  k_cvt<<<dim3((M*D_MODEL/4 + 255)/256), 256, 0, stream>>>(X, Xb, M*D_MODEL/4);
  k_cvt_w_t<<<dim3(16,16,4), 256, 0, stream>>>(
      Wq, Wk, Wv, W0, WqkvT, WqkvT + 1024*1024, WqkvT + 2*1024*1024, W0T);
  k_gemm_qkv<<<dim3(3072/128, M/128), 256, 0, stream>>>(Xb, WqkvT, QKVb, scaleQ);
  k_trans_v<<<dim3(SEQ/64, BATCH*NH), 256, 0, stream>>>(QKVb, Vt);
  k_attn<<<dim3(SEQ/64, BATCH*NH), 512, 0, stream>>>(QKVb, Vt, AO);
  k_gemm_out<<<dim3(1024/128, M/64), 256, 0, stream>>>(AO, W0T, out);
}

// Round 8
// 127.092 us; speedup vs baseline: 1.1075x; 1.0453x over previous
//
#include <hip/hip_runtime.h>

#define D_MODEL 1024
#define SEQ     2048
#define BATCH   2
#define NH      16

using u16 = unsigned short;
typedef __bf16 bf16x8 __attribute__((ext_vector_type(8)));
typedef float  f32x4  __attribute__((ext_vector_type(4)));
typedef short  short4v __attribute__((ext_vector_type(4)));
typedef short  short8v __attribute__((ext_vector_type(8)));

__device__ __forceinline__ u16 f2bf(float f){
  union { __bf16 h; u16 u; } v; v.h = (__bf16)f; return v.u;
}

__device__ __forceinline__ void gload_lds16(const void* g, void* l){
  __builtin_amdgcn_global_load_lds(
      (const __attribute__((address_space(1))) void*)g,
      (__attribute__((address_space(3))) void*)l, 16, 0, 0);
}

// ---------- kernel 1: fp32 -> bf16 (X) ----------
__global__ __launch_bounds__(256) void k_cvt(const float* __restrict__ in,
                                             u16* __restrict__ out, int n4){
  int i = blockIdx.x*256 + threadIdx.x;
  if (i >= n4) return;
  float4 v = ((const float4*)in)[i];
  ushort4 o; o.x=f2bf(v.x); o.y=f2bf(v.y); o.z=f2bf(v.z); o.w=f2bf(v.w);
  ((ushort4*)out)[i] = o;
}

// ---------- kernel 2: weight fp32[K][N] -> bf16 transposed [N][K] ----------
__global__ __launch_bounds__(256) void k_cvt_w_t(
    const float* __restrict__ wq, const float* __restrict__ wk,
    const float* __restrict__ wv, const float* __restrict__ w0,
    u16* __restrict__ oq, u16* __restrict__ ok,
    u16* __restrict__ ov, u16* __restrict__ o0){
  const float* W; u16* O;
  if      (blockIdx.z==0){W=wq;O=oq;}
  else if (blockIdx.z==1){W=wk;O=ok;}
  else if (blockIdx.z==2){W=wv;O=ov;}
  else               {W=w0;O=o0;}
  __shared__ float T[64][65];
  int t = threadIdx.x;
  int r0 = t>>4, cb = (t&15)*4;
  int kt = blockIdx.y*64, nt = blockIdx.x*64;
  #pragma unroll
  for (int j=0;j<4;++j){
    int r = r0 + j*16;
    float4 v = *(const float4*)(W + (size_t)(kt + r)*1024 + nt + cb);
    T[r][cb] = v.x; T[r][cb+1] = v.y; T[r][cb+2] = v.z; T[r][cb+3] = v.w;
  }
  __syncthreads();
  #pragma unroll
  for (int j=0;j<4;++j){
    int rn = r0 + j*16;
    ushort4 o;
    o.x = f2bf(T[cb  ][rn]); o.y = f2bf(T[cb+1][rn]);
    o.z = f2bf(T[cb+2][rn]); o.w = f2bf(T[cb+3][rn]);
    *(ushort4*)(O + (size_t)(nt + rn)*1024 + kt + cb) = o;
  }
}

// ---------- kernel 3: fused QKV GEMM  QKV[M,3072] = X[M,1024] @ WqkvT^T ----
// 128x128 tile, 2-phase dbuf, XCD-swizzled blockIdx (nwg=768, %8==0).
__global__ __launch_bounds__(256) void k_gemm_qkv(
    const u16* __restrict__ A, const u16* __restrict__ Bt,
    u16* __restrict__ Ob, float scaleQ)
{
  const int K = 1024, N = 3072;
  const int nwg = gridDim.x * gridDim.y;
  const int f = blockIdx.y * gridDim.x + blockIdx.x;
  const int sw = (f & 7) * (nwg >> 3) + (f >> 3);
  const int bxs = sw % gridDim.x, bys = sw / gridDim.x;
  const int bm = bys*128, bn = bxs*128;
  const float scl = (bn < 1024) ? scaleQ : 1.0f;
  const int lane = threadIdx.x & 63, w = threadIdx.x >> 6;
  const int hi = lane >> 4, c = lane & 15;
  const int wr = w >> 1, wc = w & 1;

  __shared__ u16 As[2][128*32];
  __shared__ u16 Bs[2][128*32];

  const int i0 = 2*w, i1 = 2*w+1;
  const int rA0 = i0*16 + (lane>>2), rA1 = i1*16 + (lane>>2);
  const int cA  = (lane&3)*8;
  const u16* aS0 = A  + (size_t)(bm + rA0)*K + cA;
  const u16* aS1 = A  + (size_t)(bm + rA1)*K + cA;
  const u16* bS0 = Bt + (size_t)(bn + rA0)*K + cA;
  const u16* bS1 = Bt + (size_t)(bn + rA1)*K + cA;

  auto stage = [&](int buf, int kk){
    gload_lds16(aS0 + kk, As[buf] + i0*512);
    gload_lds16(aS1 + kk, As[buf] + i1*512);
    gload_lds16(bS0 + kk, Bs[buf] + i0*512);
    gload_lds16(bS1 + kk, Bs[buf] + i1*512);
  };

  f32x4 acc[4][4];
  #pragma unroll
  for (int mi=0;mi<4;++mi)
    #pragma unroll
    for (int ni=0;ni<4;++ni) acc[mi][ni] = (f32x4){0.f,0.f,0.f,0.f};

  stage(0, 0);
  __syncthreads();
  int cur = 0;
  for (int kk = 0; kk < K; kk += 32){
    if (kk + 32 < K) stage(cur^1, kk + 32);
    const u16* as = As[cur];
    const u16* bs = Bs[cur];
    bf16x8 af[4], bfr[4];
    #pragma unroll
    for (int mi=0;mi<4;++mi)
      af[mi] = *(const bf16x8*)(as + (wr*64 + mi*16 + c)*32 + hi*8);
    #pragma unroll
    for (int ni=0;ni<4;++ni)
      bfr[ni] = *(const bf16x8*)(bs + (wc*64 + ni*16 + c)*32 + hi*8);
    #pragma unroll
    for (int mi=0;mi<4;++mi)
      #pragma unroll
      for (int ni=0;ni<4;++ni)
        acc[mi][ni] = __builtin_amdgcn_mfma_f32_16x16x32_bf16(af[mi], bfr[ni], acc[mi][ni], 0, 0, 0);
    __syncthreads();
    cur ^= 1;
  }
  #pragma unroll
  for (int mi=0;mi<4;++mi){
    #pragma unroll
    for (int ni=0;ni<4;++ni){
      int row = bm + wr*64 + mi*16 + hi*4;
      int col = bn + wc*64 + ni*16 + c;
      #pragma unroll
      for (int r=0;r<4;++r)
        Ob[(size_t)(row + r)*N + col] = f2bf(acc[mi][ni][r] * scl);
    }
  }
}

// ---------- kernel 6: out-proj GEMM  C[M,1024] = AO @ W0T^T (fp32 out) -----
// 128x128 tile (back to R2 config), XCD-swizzled (nwg=256, %8==0).
__global__ __launch_bounds__(256) void k_gemm_out(
    const u16* __restrict__ A, const u16* __restrict__ Bt,
    float* __restrict__ OF)
{
  const int K = 1024, N = 1024;
  const int nwg = gridDim.x * gridDim.y;
  const int f = blockIdx.y * gridDim.x + blockIdx.x;
  const int sw = (f & 7) * (nwg >> 3) + (f >> 3);
  const int bxs = sw % gridDim.x, bys = sw / gridDim.x;
  const int bm = bys*128, bn = bxs*128;
  const int lane = threadIdx.x & 63, w = threadIdx.x >> 6;
  const int hi = lane >> 4, c = lane & 15;
  const int wr = w >> 1, wc = w & 1;

  __shared__ u16 As[2][128*32];
  __shared__ u16 Bs[2][128*32];

  const int i0 = 2*w, i1 = 2*w+1;
  const int rA0 = i0*16 + (lane>>2), rA1 = i1*16 + (lane>>2);
  const int cA  = (lane&3)*8;
  const u16* aS0 = A  + (size_t)(bm + rA0)*K + cA;
  const u16* aS1 = A  + (size_t)(bm + rA1)*K + cA;
  const u16* bS0 = Bt + (size_t)(bn + rA0)*K + cA;
  const u16* bS1 = Bt + (size_t)(bn + rA1)*K + cA;

  auto stage = [&](int buf, int kk){
    gload_lds16(aS0 + kk, As[buf] + i0*512);
    gload_lds16(aS1 + kk, As[buf] + i1*512);
    gload_lds16(bS0 + kk, Bs[buf] + i0*512);
    gload_lds16(bS1 + kk, Bs[buf] + i1*512);
  };

  f32x4 acc[4][4];
  #pragma unroll
  for (int mi=0;mi<4;++mi)
    #pragma unroll
    for (int ni=0;ni<4;++ni) acc[mi][ni] = (f32x4){0.f,0.f,0.f,0.f};

  stage(0, 0);
  __syncthreads();
  int cur = 0;
  for (int kk = 0; kk < K; kk += 32){
    if (kk + 32 < K) stage(cur^1, kk + 32);
    const u16* as = As[cur];
    const u16* bs = Bs[cur];
    bf16x8 af[4], bfr[4];
    #pragma unroll
    for (int mi=0;mi<4;++mi)
      af[mi] = *(const bf16x8*)(as + (wr*64 + mi*16 + c)*32 + hi*8);
    #pragma unroll
    for (int ni=0;ni<4;++ni)
      bfr[ni] = *(const bf16x8*)(bs + (wc*64 + ni*16 + c)*32 + hi*8);
    #pragma unroll
    for (int mi=0;mi<4;++mi)
      #pragma unroll
      for (int ni=0;ni<4;++ni)
        acc[mi][ni] = __builtin_amdgcn_mfma_f32_16x16x32_bf16(af[mi], bfr[ni], acc[mi][ni], 0, 0, 0);
    __syncthreads();
    cur ^= 1;
  }
  #pragma unroll
  for (int mi=0;mi<4;++mi){
    #pragma unroll
    for (int ni=0;ni<4;++ni){
      int row = bm + wr*64 + mi*16 + hi*4;
      int col = bn + wc*64 + ni*16 + c;
      #pragma unroll
      for (int r=0;r<4;++r)
        OF[(size_t)(row + r)*N + col] = acc[mi][ni][r];
    }
  }
}

// ---------- kernel 4: V (QKV col 2048+) -> Vt [B*H][64][S-permuted] --------
// Key order inside each 64-key tile is permuted: pos = [kh hi1 hi0 t j1 j0]
// for key s = [kh t hi1 hi0 j1 j0], so the attention PV B-fragment
// (keys {t*16+hi*4+j, t=0,1}) is ONE contiguous 16B block per lane ->
// b128 V-reads with the same conflict-free o-structure as K-reads.
__global__ __launch_bounds__(256) void k_trans_v(const u16* __restrict__ QKV,
                                                 u16* __restrict__ Vt){
  int st = blockIdx.x, bh = blockIdx.y;
  int b = bh >> 4, h = bh & 15;
  __shared__ u16 T[64][80];
  int t = threadIdx.x;
  {
    int s = t >> 2, dc = (t & 3)*16;
    const u16* src = QKV + (size_t)(b*SEQ + st*64 + s)*3072 + 2048 + h*64 + dc;
    *(uint4*)&T[s][dc]   = *(const uint4*)(src);
    *(uint4*)&T[s][dc+8] = *(const uint4*)(src + 8);
  }
  __syncthreads();
  {
    int d = t >> 2, sc = (t & 3)*16;
    u16* dst = Vt + ((size_t)bh*64 + d)*SEQ + st*64 + sc;
    u16 vals[16];
    #pragma unroll
    for (int x=0;x<16;++x){
      int p = sc + x;
      int s = (p & 0x23) | ((p & 0x04) << 2) | ((p & 0x18) >> 1);
      vals[x] = T[s][d];
    }
    uint4 w0, w1;
    w0.x = (unsigned)vals[ 0] | ((unsigned)vals[ 1] << 16);
    w0.y = (unsigned)vals[ 2] | ((unsigned)vals[ 3] << 16);
    w0.z = (unsigned)vals[ 4] | ((unsigned)vals[ 5] << 16);
    w0.w = (unsigned)vals[ 6] | ((unsigned)vals[ 7] << 16);
    w1.x = (unsigned)vals[ 8] | ((unsigned)vals[ 9] << 16);
    w1.y = (unsigned)vals[10] | ((unsigned)vals[11] << 16);
    w1.z = (unsigned)vals[12] | ((unsigned)vals[13] << 16);
    w1.w = (unsigned)vals[14] | ((unsigned)vals[15] << 16);
    *(uint4*)(dst)     = w0;
    *(uint4*)(dst + 8) = w1;
  }
}

// ---------- kernel 5: attention ----------
// grid (bh, qt): all q-blocks of one head land on XCD bh%8 (hardware
// round-robins linear blockIdx) -> per-head K/V stays L2-resident on one XCD.
// 8 waves = (4 q-groups) x (2 key-halves); 16 q x 32 keys per wave per tile.
// SWAPPED QK^T: s = mfma(K,Q) -> lane (c,hi) holds P[q=c][key=t*16+hi*4+i]
// = the PV A-fragment. exp2+pack in-register; PV via K=16 MFMAs; V keys
// pre-permuted (k_trans_v) so each lane's PV B-frag is one b128 read.
__global__ __launch_bounds__(512, 8) void k_attn(const u16* __restrict__ QKV,
                                                 const u16* __restrict__ Vt,
                                                 u16* __restrict__ AO)
{
  const int bh = blockIdx.x, qt = blockIdx.y;
  const int b = bh >> 4, h = bh & 15;
  const int lane = threadIdx.x & 63, w = threadIdx.x >> 6;
  const int qg = w >> 1, kh = w & 1;
  const int hi = lane >> 4, c = lane & 15;

  __shared__ u16 Ks[2][64*64];   // [key][dim] rows 128B, source-swizzled
  __shared__ u16 Vs[2][64*64];   // [dim][key'] rows 128B, source-swizzled

  const size_t qrow = (size_t)(b*SEQ + qt*64 + qg*16 + c);
  const bf16x8 qf0 = *(const bf16x8*)(QKV + qrow*3072 + h*64 + hi*8);
  const bf16x8 qf1 = *(const bf16x8*)(QKV + qrow*3072 + h*64 + 32 + hi*8);

  const short4v ones4 = {(short)0x3F80,(short)0x3F80,(short)0x3F80,(short)0x3F80};

  f32x4 acc_o[4];
  #pragma unroll
  for (int n=0;n<4;++n) acc_o[n] = (f32x4){0.f,0.f,0.f,0.f};
  f32x4 acc_l = (f32x4){0.f,0.f,0.f,0.f};

  // staging: wave w loads rows w*8..w*8+7 of the 64-row K tile and V tile
  const int r = w*8 + (lane>>3);
  const int sb = ((((lane&7)*16) ^ ((lane>>3)<<4)) >> 1);  // u16 units
  const u16* kSrc = QKV + (size_t)(b*SEQ + r)*3072 + 1024 + h*64 + sb;
  const u16* vSrc = Vt + ((size_t)bh*64 + r)*SEQ + sb;

  auto stage = [&](int buf){
    gload_lds16(kSrc, Ks[buf] + w*512);
    gload_lds16(vSrc, Vs[buf] + w*512);
    kSrc += (size_t)64*3072; vSrc += 64;
  };

  // hoisted LDS read bases; XOR applied to full byte-within-row offset
  const int swz = ((c&7)<<4);
  const char* kr0 = (const char*)&Ks[0][0] + (kh*32 + c)*128 + (( 0 + hi*16) ^ swz);
  const char* kr1 = (const char*)&Ks[0][0] + (kh*32 + c)*128 + ((64 + hi*16) ^ swz);
  // V B-frag: one b128 per n: row=c, 16B block at (kh*64 + hi*16)^swz;
  // block = [t0:j0..3 | t1:j0..3] thanks to the key permutation.
  const char* vr  = (const char*)&Vs[0][0] + c*128 + ((kh*64 + hi*16) ^ swz);

  auto body = [&](int buf){
    const int bo = buf*8192;
    f32x4 s0 = (f32x4){0.f,0.f,0.f,0.f};
    f32x4 s1 = (f32x4){0.f,0.f,0.f,0.f};
    bf16x8 k00 = *(const bf16x8*)(kr0 + bo);
    bf16x8 k01 = *(const bf16x8*)(kr1 + bo);
    bf16x8 k10 = *(const bf16x8*)(kr0 + bo + 2048);
    bf16x8 k11 = *(const bf16x8*)(kr1 + bo + 2048);
    __builtin_amdgcn_s_setprio(1);
    s0 = __builtin_amdgcn_mfma_f32_16x16x32_bf16(k00, qf0, s0, 0,0,0);
    s1 = __builtin_amdgcn_mfma_f32_16x16x32_bf16(k10, qf0, s1, 0,0,0);
    s0 = __builtin_amdgcn_mfma_f32_16x16x32_bf16(k01, qf1, s0, 0,0,0);
    s1 = __builtin_amdgcn_mfma_f32_16x16x32_bf16(k11, qf1, s1, 0,0,0);
    __builtin_amdgcn_s_setprio(0);

    // exp2 + pack into PV A-fragments (lane-local, no cross-lane movement)
    short4v a0, a1;
    #pragma unroll
    for (int i=0;i<4;++i){
      a0[i] = (short)f2bf(__builtin_amdgcn_exp2f(s0[i]));
      a1[i] = (short)f2bf(__builtin_amdgcn_exp2f(s1[i]));
    }

    __builtin_amdgcn_s_setprio(1);
    acc_l = __builtin_amdgcn_mfma_f32_16x16x16bf16_1k(a0, ones4, acc_l, 0,0,0);
    acc_l = __builtin_amdgcn_mfma_f32_16x16x16bf16_1k(a1, ones4, acc_l, 0,0,0);
    #pragma unroll
    for (int n=0;n<4;++n){
      short8v vv = *(const short8v*)(vr + bo + n*2048);
      short4v v0 = __builtin_shufflevector(vv, vv, 0,1,2,3);
      short4v v1 = __builtin_shufflevector(vv, vv, 4,5,6,7);
      acc_o[n] = __builtin_amdgcn_mfma_f32_16x16x16bf16_1k(a0, v0, acc_o[n], 0,0,0);
      acc_o[n] = __builtin_amdgcn_mfma_f32_16x16x16bf16_1k(a1, v1, acc_o[n], 0,0,0);
    }
    __builtin_amdgcn_s_setprio(0);
  };

  stage(0);
  __syncthreads();
  #pragma unroll 1
  for (int u = 0; u < SEQ/128; ++u){
    stage(1);
    body(0);
    __syncthreads();
    if (u != SEQ/128 - 1) stage(0);
    body(1);
    __syncthreads();
  }

  // merge key-halves: kh=1 writes partials to LDS, kh=0 adds + normalizes
  float* Of = (float*)&Ks[0][0];           // [qg][16][64] f32 = 16KB
  float* Lf = (float*)&Vs[0][0];           // [qg][16]
  if (kh == 1){
    #pragma unroll
    for (int n=0;n<4;++n)
      #pragma unroll
      for (int i=0;i<4;++i)
        Of[qg*1024 + (hi*4+i)*64 + n*16 + c] = acc_o[n][i];
    if (c == 0){
      #pragma unroll
      for (int i=0;i<4;++i) Lf[qg*16 + hi*4 + i] = acc_l[i];
    }
  }
  __syncthreads();
  if (kh == 0){
    float inv[4];
    #pragma unroll
    for (int i=0;i<4;++i)
      inv[i] = 1.0f / (acc_l[i] + Lf[qg*16 + hi*4 + i]);
    size_t obase = (size_t)(b*SEQ + qt*64 + qg*16 + hi*4)*D_MODEL + h*64;
    #pragma unroll
    for (int i=0;i<4;++i){
      #pragma unroll
      for (int n=0;n<4;++n){
        float o = acc_o[n][i] + Of[qg*1024 + (hi*4+i)*64 + n*16 + c];
        AO[obase + (size_t)i*D_MODEL + n*16 + c] = f2bf(o * inv[i]);
      }
    }
  }
}

extern "C" void kernel_launch(void* const* d_in, const int* in_sizes, int n_in,
                              void* d_out, int out_size, void* d_ws, size_t ws_size,
                              hipStream_t stream)
{
  const float* X  = (const float*)d_in[0];
  const float* Wq = (const float*)d_in[1];
  const float* Wk = (const float*)d_in[2];
  const float* Wv = (const float*)d_in[3];
  const float* W0 = (const float*)d_in[4];
  float* out = (float*)d_out;

  char* ws = (char*)d_ws;
  const size_t MB = 1024*1024;
  u16* Xb    = (u16*)(ws);           // 8 MB  [4096][1024]; reused as AO later
  u16* WqkvT = (u16*)(ws +  8*MB);   // 6 MB  [3072][1024] (Wq,Wk,Wv rows)
  u16* W0T   = (u16*)(ws + 14*MB);   // 2 MB
  u16* QKVb  = (u16*)(ws + 16*MB);   // 24 MB [4096][3072]
  u16* Vt    = (u16*)(ws + 40*MB);   // 8 MB  [B*H][64][SEQ] (keys permuted)
  u16* AO    = Xb;                   // Xb dead after QKV GEMM

  const float scaleQ = 1.4426950408889634f / sqrtf((float)SEQ);
  const int M = BATCH*SEQ;

  k_cvt<<<dim3((M*D_MODEL/4 + 255)/256), 256, 0, stream>>>(X, Xb, M*D_MODEL/4);
  k_cvt_w_t<<<dim3(16,16,4), 256, 0, stream>>>(
      Wq, Wk, Wv, W0, WqkvT, WqkvT + 1024*1024, WqkvT + 2*1024*1024, W0T);
  k_gemm_qkv<<<dim3(3072/128, M/128), 256, 0, stream>>>(Xb, WqkvT, QKVb, scaleQ);
  k_trans_v<<<dim3(SEQ/64, BATCH*NH), 256, 0, stream>>>(QKVb, Vt);
  k_attn<<<dim3(BATCH*NH, SEQ/64), 512, 0, stream>>>(QKVb, Vt, AO);
  k_gemm_out<<<dim3(1024/128, M/128), 256, 0, stream>>>(AO, W0T, out);
}

// Round 9
// 117.330 us; speedup vs baseline: 1.1997x; 1.0832x over previous
//
#include <hip/hip_runtime.h>

#define D_MODEL 1024
#define SEQ     2048
#define BATCH   2
#define NH      16

using u16 = unsigned short;
typedef __bf16 bf16x8 __attribute__((ext_vector_type(8)));
typedef float  f32x4  __attribute__((ext_vector_type(4)));
typedef short  short4v __attribute__((ext_vector_type(4)));
typedef short  short8v __attribute__((ext_vector_type(8)));

__device__ __forceinline__ u16 f2bf(float f){
  union { __bf16 h; u16 u; } v; v.h = (__bf16)f; return v.u;
}

__device__ __forceinline__ void gload_lds16(const void* g, void* l){
  __builtin_amdgcn_global_load_lds(
      (const __attribute__((address_space(1))) void*)g,
      (__attribute__((address_space(3))) void*)l, 16, 0, 0);
}

// ---------- kernel 1: fp32 -> bf16 (X) ----------
__global__ __launch_bounds__(256) void k_cvt(const float* __restrict__ in,
                                             u16* __restrict__ out, int n4){
  int i = blockIdx.x*256 + threadIdx.x;
  if (i >= n4) return;
  float4 v = ((const float4*)in)[i];
  ushort4 o; o.x=f2bf(v.x); o.y=f2bf(v.y); o.z=f2bf(v.z); o.w=f2bf(v.w);
  ((ushort4*)out)[i] = o;
}

// ---------- kernel 2: weight fp32[K][N] -> bf16 transposed [N][K] ----------
__global__ __launch_bounds__(256) void k_cvt_w_t(
    const float* __restrict__ wq, const float* __restrict__ wk,
    const float* __restrict__ wv, const float* __restrict__ w0,
    u16* __restrict__ oq, u16* __restrict__ ok,
    u16* __restrict__ ov, u16* __restrict__ o0){
  const float* W; u16* O;
  if      (blockIdx.z==0){W=wq;O=oq;}
  else if (blockIdx.z==1){W=wk;O=ok;}
  else if (blockIdx.z==2){W=wv;O=ov;}
  else               {W=w0;O=o0;}
  __shared__ float T[64][65];
  int t = threadIdx.x;
  int r0 = t>>4, cb = (t&15)*4;
  int kt = blockIdx.y*64, nt = blockIdx.x*64;
  #pragma unroll
  for (int j=0;j<4;++j){
    int r = r0 + j*16;
    float4 v = *(const float4*)(W + (size_t)(kt + r)*1024 + nt + cb);
    T[r][cb] = v.x; T[r][cb+1] = v.y; T[r][cb+2] = v.z; T[r][cb+3] = v.w;
  }
  __syncthreads();
  #pragma unroll
  for (int j=0;j<4;++j){
    int rn = r0 + j*16;
    ushort4 o;
    o.x = f2bf(T[cb  ][rn]); o.y = f2bf(T[cb+1][rn]);
    o.z = f2bf(T[cb+2][rn]); o.w = f2bf(T[cb+3][rn]);
    *(ushort4*)(O + (size_t)(nt + rn)*1024 + kt + cb) = o;
  }
}

// ---------- kernel 3: fused QKV GEMM  QKV[M,3072] = X[M,1024] @ WqkvT^T ----
// 128x128 tile, 2-phase dbuf, XCD-swizzled blockIdx (nwg=768, %8==0).
__global__ __launch_bounds__(256) void k_gemm_qkv(
    const u16* __restrict__ A, const u16* __restrict__ Bt,
    u16* __restrict__ Ob, float scaleQ)
{
  const int K = 1024, N = 3072;
  const int nwg = gridDim.x * gridDim.y;
  const int f = blockIdx.y * gridDim.x + blockIdx.x;
  const int sw = (f & 7) * (nwg >> 3) + (f >> 3);
  const int bxs = sw % gridDim.x, bys = sw / gridDim.x;
  const int bm = bys*128, bn = bxs*128;
  const float scl = (bn < 1024) ? scaleQ : 1.0f;
  const int lane = threadIdx.x & 63, w = threadIdx.x >> 6;
  const int hi = lane >> 4, c = lane & 15;
  const int wr = w >> 1, wc = w & 1;

  __shared__ u16 As[2][128*32];
  __shared__ u16 Bs[2][128*32];

  const int i0 = 2*w, i1 = 2*w+1;
  const int rA0 = i0*16 + (lane>>2), rA1 = i1*16 + (lane>>2);
  const int cA  = (lane&3)*8;
  const u16* aS0 = A  + (size_t)(bm + rA0)*K + cA;
  const u16* aS1 = A  + (size_t)(bm + rA1)*K + cA;
  const u16* bS0 = Bt + (size_t)(bn + rA0)*K + cA;
  const u16* bS1 = Bt + (size_t)(bn + rA1)*K + cA;

  auto stage = [&](int buf, int kk){
    gload_lds16(aS0 + kk, As[buf] + i0*512);
    gload_lds16(aS1 + kk, As[buf] + i1*512);
    gload_lds16(bS0 + kk, Bs[buf] + i0*512);
    gload_lds16(bS1 + kk, Bs[buf] + i1*512);
  };

  f32x4 acc[4][4];
  #pragma unroll
  for (int mi=0;mi<4;++mi)
    #pragma unroll
    for (int ni=0;ni<4;++ni) acc[mi][ni] = (f32x4){0.f,0.f,0.f,0.f};

  stage(0, 0);
  __syncthreads();
  int cur = 0;
  for (int kk = 0; kk < K; kk += 32){
    if (kk + 32 < K) stage(cur^1, kk + 32);
    const u16* as = As[cur];
    const u16* bs = Bs[cur];
    bf16x8 af[4], bfr[4];
    #pragma unroll
    for (int mi=0;mi<4;++mi)
      af[mi] = *(const bf16x8*)(as + (wr*64 + mi*16 + c)*32 + hi*8);
    #pragma unroll
    for (int ni=0;ni<4;++ni)
      bfr[ni] = *(const bf16x8*)(bs + (wc*64 + ni*16 + c)*32 + hi*8);
    #pragma unroll
    for (int mi=0;mi<4;++mi)
      #pragma unroll
      for (int ni=0;ni<4;++ni)
        acc[mi][ni] = __builtin_amdgcn_mfma_f32_16x16x32_bf16(af[mi], bfr[ni], acc[mi][ni], 0, 0, 0);
    __syncthreads();
    cur ^= 1;
  }
  #pragma unroll
  for (int mi=0;mi<4;++mi){
    #pragma unroll
    for (int ni=0;ni<4;++ni){
      int row = bm + wr*64 + mi*16 + hi*4;
      int col = bn + wc*64 + ni*16 + c;
      #pragma unroll
      for (int r=0;r<4;++r)
        Ob[(size_t)(row + r)*N + col] = f2bf(acc[mi][ni][r] * scl);
    }
  }
}

// ---------- kernel 6: out-proj GEMM  C[M,1024] = AO @ W0T^T (fp32 out) -----
// 128x128 tile, XCD-swizzled (nwg=256, %8==0).
__global__ __launch_bounds__(256) void k_gemm_out(
    const u16* __restrict__ A, const u16* __restrict__ Bt,
    float* __restrict__ OF)
{
  const int K = 1024, N = 1024;
  const int nwg = gridDim.x * gridDim.y;
  const int f = blockIdx.y * gridDim.x + blockIdx.x;
  const int sw = (f & 7) * (nwg >> 3) + (f >> 3);
  const int bxs = sw % gridDim.x, bys = sw / gridDim.x;
  const int bm = bys*128, bn = bxs*128;
  const int lane = threadIdx.x & 63, w = threadIdx.x >> 6;
  const int hi = lane >> 4, c = lane & 15;
  const int wr = w >> 1, wc = w & 1;

  __shared__ u16 As[2][128*32];
  __shared__ u16 Bs[2][128*32];

  const int i0 = 2*w, i1 = 2*w+1;
  const int rA0 = i0*16 + (lane>>2), rA1 = i1*16 + (lane>>2);
  const int cA  = (lane&3)*8;
  const u16* aS0 = A  + (size_t)(bm + rA0)*K + cA;
  const u16* aS1 = A  + (size_t)(bm + rA1)*K + cA;
  const u16* bS0 = Bt + (size_t)(bn + rA0)*K + cA;
  const u16* bS1 = Bt + (size_t)(bn + rA1)*K + cA;

  auto stage = [&](int buf, int kk){
    gload_lds16(aS0 + kk, As[buf] + i0*512);
    gload_lds16(aS1 + kk, As[buf] + i1*512);
    gload_lds16(bS0 + kk, Bs[buf] + i0*512);
    gload_lds16(bS1 + kk, Bs[buf] + i1*512);
  };

  f32x4 acc[4][4];
  #pragma unroll
  for (int mi=0;mi<4;++mi)
    #pragma unroll
    for (int ni=0;ni<4;++ni) acc[mi][ni] = (f32x4){0.f,0.f,0.f,0.f};

  stage(0, 0);
  __syncthreads();
  int cur = 0;
  for (int kk = 0; kk < K; kk += 32){
    if (kk + 32 < K) stage(cur^1, kk + 32);
    const u16* as = As[cur];
    const u16* bs = Bs[cur];
    bf16x8 af[4], bfr[4];
    #pragma unroll
    for (int mi=0;mi<4;++mi)
      af[mi] = *(const bf16x8*)(as + (wr*64 + mi*16 + c)*32 + hi*8);
    #pragma unroll
    for (int ni=0;ni<4;++ni)
      bfr[ni] = *(const bf16x8*)(bs + (wc*64 + ni*16 + c)*32 + hi*8);
    #pragma unroll
    for (int mi=0;mi<4;++mi)
      #pragma unroll
      for (int ni=0;ni<4;++ni)
        acc[mi][ni] = __builtin_amdgcn_mfma_f32_16x16x32_bf16(af[mi], bfr[ni], acc[mi][ni], 0, 0, 0);
    __syncthreads();
    cur ^= 1;
  }
  #pragma unroll
  for (int mi=0;mi<4;++mi){
    #pragma unroll
    for (int ni=0;ni<4;++ni){
      int row = bm + wr*64 + mi*16 + hi*4;
      int col = bn + wc*64 + ni*16 + c;
      #pragma unroll
      for (int r=0;r<4;++r)
        OF[(size_t)(row + r)*N + col] = acc[mi][ni][r];
    }
  }
}

// ---------- kernel 4: V (QKV col 2048+) -> Vt [B*H][64][S-permuted] --------
// Key order inside each 64-key tile is permuted: pos = [kh hi1 hi0 t j1 j0]
// for key s = [kh t hi1 hi0 j1 j0], so the attention PV B-fragment
// (keys {t*16+hi*4+j, t=0,1}) is ONE contiguous 16B block per lane ->
// b128 V-reads with the same conflict-free o-structure as K-reads.
__global__ __launch_bounds__(256) void k_trans_v(const u16* __restrict__ QKV,
                                                 u16* __restrict__ Vt){
  int st = blockIdx.x, bh = blockIdx.y;
  int b = bh >> 4, h = bh & 15;
  __shared__ u16 T[64][80];
  int t = threadIdx.x;
  {
    int s = t >> 2, dc = (t & 3)*16;
    const u16* src = QKV + (size_t)(b*SEQ + st*64 + s)*3072 + 2048 + h*64 + dc;
    *(uint4*)&T[s][dc]   = *(const uint4*)(src);
    *(uint4*)&T[s][dc+8] = *(const uint4*)(src + 8);
  }
  __syncthreads();
  {
    int d = t >> 2, sc = (t & 3)*16;
    u16* dst = Vt + ((size_t)bh*64 + d)*SEQ + st*64 + sc;
    u16 vals[16];
    #pragma unroll
    for (int x=0;x<16;++x){
      int p = sc + x;
      int s = (p & 0x23) | ((p & 0x04) << 2) | ((p & 0x18) >> 1);
      vals[x] = T[s][d];
    }
    uint4 w0, w1;
    w0.x = (unsigned)vals[ 0] | ((unsigned)vals[ 1] << 16);
    w0.y = (unsigned)vals[ 2] | ((unsigned)vals[ 3] << 16);
    w0.z = (unsigned)vals[ 4] | ((unsigned)vals[ 5] << 16);
    w0.w = (unsigned)vals[ 6] | ((unsigned)vals[ 7] << 16);
    w1.x = (unsigned)vals[ 8] | ((unsigned)vals[ 9] << 16);
    w1.y = (unsigned)vals[10] | ((unsigned)vals[11] << 16);
    w1.z = (unsigned)vals[12] | ((unsigned)vals[13] << 16);
    w1.w = (unsigned)vals[14] | ((unsigned)vals[15] << 16);
    *(uint4*)(dst)     = w0;
    *(uint4*)(dst + 8) = w1;
  }
}

// ---------- kernel 5: attention ----------
// 32 q-rows PER WAVE: block = 128 q (4 qg x 2 qh x 16), 8 waves (4qg x 2kh).
// Halves LDS-read traffic and barriers per FLOP vs 16q/wave: the same
// 4 K-frag + 4 V-frag b128 reads now serve 32q x 32keys.
// grid (bh, qt): head-affine XCD mapping (per-head K/V L2-resident).
// SWAPPED QK^T: s = mfma(K,Q); exp2+pack in-register; PV via K=16 MFMAs;
// lsum via ones-B MFMA; kh-halves merge additively in two qh passes.
__global__ __launch_bounds__(512, 4) void k_attn(const u16* __restrict__ QKV,
                                                 const u16* __restrict__ Vt,
                                                 u16* __restrict__ AO)
{
  const int bh = blockIdx.x, qt = blockIdx.y;
  const int b = bh >> 4, h = bh & 15;
  const int lane = threadIdx.x & 63, w = threadIdx.x >> 6;
  const int qg = w >> 1, kh = w & 1;
  const int hi = lane >> 4, c = lane & 15;

  __shared__ u16 Ks[2][64*64];   // [key][dim] rows 128B, source-swizzled
  __shared__ u16 Vs[2][64*64];   // [dim][key'] rows 128B, source-swizzled

  const size_t qbase = (size_t)(b*SEQ + qt*128 + qg*32 + c);
  const bf16x8 qA0 = *(const bf16x8*)(QKV + (qbase     )*3072 + h*64 + hi*8);
  const bf16x8 qA1 = *(const bf16x8*)(QKV + (qbase     )*3072 + h*64 + 32 + hi*8);
  const bf16x8 qB0 = *(const bf16x8*)(QKV + (qbase + 16)*3072 + h*64 + hi*8);
  const bf16x8 qB1 = *(const bf16x8*)(QKV + (qbase + 16)*3072 + h*64 + 32 + hi*8);

  const short4v ones4 = {(short)0x3F80,(short)0x3F80,(short)0x3F80,(short)0x3F80};

  f32x4 acc_o0[4], acc_o1[4];
  #pragma unroll
  for (int n=0;n<4;++n){ acc_o0[n] = (f32x4){0.f,0.f,0.f,0.f};
                         acc_o1[n] = (f32x4){0.f,0.f,0.f,0.f}; }
  f32x4 acc_l0 = (f32x4){0.f,0.f,0.f,0.f};
  f32x4 acc_l1 = (f32x4){0.f,0.f,0.f,0.f};

  // staging: wave w loads rows w*8..w*8+7 of the 64-row K tile and V tile
  const int r = w*8 + (lane>>3);
  const int sb = ((((lane&7)*16) ^ ((lane>>3)<<4)) >> 1);  // u16 units
  const u16* kSrc = QKV + (size_t)(b*SEQ + r)*3072 + 1024 + h*64 + sb;
  const u16* vSrc = Vt + ((size_t)bh*64 + r)*SEQ + sb;

  auto stage = [&](int buf){
    gload_lds16(kSrc, Ks[buf] + w*512);
    gload_lds16(vSrc, Vs[buf] + w*512);
    kSrc += (size_t)64*3072; vSrc += 64;
  };

  // hoisted LDS read bases; XOR applied to full byte-within-row offset
  const int swz = ((c&7)<<4);
  const char* kr0 = (const char*)&Ks[0][0] + (kh*32 + c)*128 + (( 0 + hi*16) ^ swz);
  const char* kr1 = (const char*)&Ks[0][0] + (kh*32 + c)*128 + ((64 + hi*16) ^ swz);
  const char* vr  = (const char*)&Vs[0][0] + c*128 + ((kh*64 + hi*16) ^ swz);

  auto body = [&](int buf){
    const int bo = buf*8192;
    bf16x8 k00 = *(const bf16x8*)(kr0 + bo);          // keys t0, dims 0-31
    bf16x8 k01 = *(const bf16x8*)(kr1 + bo);          // keys t0, dims 32-63
    bf16x8 k10 = *(const bf16x8*)(kr0 + bo + 2048);   // keys t1, dims 0-31
    bf16x8 k11 = *(const bf16x8*)(kr1 + bo + 2048);   // keys t1, dims 32-63
    f32x4 s00 = (f32x4){0.f,0.f,0.f,0.f};  // t0, qh0
    f32x4 s10 = (f32x4){0.f,0.f,0.f,0.f};  // t1, qh0
    f32x4 s01 = (f32x4){0.f,0.f,0.f,0.f};  // t0, qh1
    f32x4 s11 = (f32x4){0.f,0.f,0.f,0.f};  // t1, qh1
    __builtin_amdgcn_s_setprio(1);
    s00 = __builtin_amdgcn_mfma_f32_16x16x32_bf16(k00, qA0, s00, 0,0,0);
    s10 = __builtin_amdgcn_mfma_f32_16x16x32_bf16(k10, qA0, s10, 0,0,0);
    s01 = __builtin_amdgcn_mfma_f32_16x16x32_bf16(k00, qB0, s01, 0,0,0);
    s11 = __builtin_amdgcn_mfma_f32_16x16x32_bf16(k10, qB0, s11, 0,0,0);
    s00 = __builtin_amdgcn_mfma_f32_16x16x32_bf16(k01, qA1, s00, 0,0,0);
    s10 = __builtin_amdgcn_mfma_f32_16x16x32_bf16(k11, qA1, s10, 0,0,0);
    s01 = __builtin_amdgcn_mfma_f32_16x16x32_bf16(k01, qB1, s01, 0,0,0);
    s11 = __builtin_amdgcn_mfma_f32_16x16x32_bf16(k11, qB1, s11, 0,0,0);
    __builtin_amdgcn_s_setprio(0);

    short4v a00, a10, a01, a11;
    #pragma unroll
    for (int i=0;i<4;++i){
      a00[i] = (short)f2bf(__builtin_amdgcn_exp2f(s00[i]));
      a10[i] = (short)f2bf(__builtin_amdgcn_exp2f(s10[i]));
      a01[i] = (short)f2bf(__builtin_amdgcn_exp2f(s01[i]));
      a11[i] = (short)f2bf(__builtin_amdgcn_exp2f(s11[i]));
    }

    __builtin_amdgcn_s_setprio(1);
    acc_l0 = __builtin_amdgcn_mfma_f32_16x16x16bf16_1k(a00, ones4, acc_l0, 0,0,0);
    acc_l0 = __builtin_amdgcn_mfma_f32_16x16x16bf16_1k(a10, ones4, acc_l0, 0,0,0);
    acc_l1 = __builtin_amdgcn_mfma_f32_16x16x16bf16_1k(a01, ones4, acc_l1, 0,0,0);
    acc_l1 = __builtin_amdgcn_mfma_f32_16x16x16bf16_1k(a11, ones4, acc_l1, 0,0,0);
    #pragma unroll
    for (int n=0;n<4;++n){
      short8v vv = *(const short8v*)(vr + bo + n*2048);
      short4v v0 = __builtin_shufflevector(vv, vv, 0,1,2,3);
      short4v v1 = __builtin_shufflevector(vv, vv, 4,5,6,7);
      acc_o0[n] = __builtin_amdgcn_mfma_f32_16x16x16bf16_1k(a00, v0, acc_o0[n], 0,0,0);
      acc_o0[n] = __builtin_amdgcn_mfma_f32_16x16x16bf16_1k(a10, v1, acc_o0[n], 0,0,0);
      acc_o1[n] = __builtin_amdgcn_mfma_f32_16x16x16bf16_1k(a01, v0, acc_o1[n], 0,0,0);
      acc_o1[n] = __builtin_amdgcn_mfma_f32_16x16x16bf16_1k(a11, v1, acc_o1[n], 0,0,0);
    }
    __builtin_amdgcn_s_setprio(0);
  };

  stage(0);
  __syncthreads();
  #pragma unroll 1
  for (int u = 0; u < SEQ/128; ++u){
    stage(1);
    body(0);
    __syncthreads();
    if (u != SEQ/128 - 1) stage(0);
    body(1);
    __syncthreads();
  }

  // merge key-halves additively, one qh pass at a time (Of = 16KB in Ks)
  float* Of = (float*)&Ks[0][0];           // [qg][16][64] f32
  float* Lf = (float*)&Vs[0][0];           // [qg][16]
  // ---- pass qh = 0 ----
  if (kh == 1){
    #pragma unroll
    for (int n=0;n<4;++n)
      #pragma unroll
      for (int i=0;i<4;++i)
        Of[qg*1024 + (hi*4+i)*64 + n*16 + c] = acc_o0[n][i];
    if (c == 0){
      #pragma unroll
      for (int i=0;i<4;++i) Lf[qg*16 + hi*4 + i] = acc_l0[i];
    }
  }
  __syncthreads();
  if (kh == 0){
    float inv[4];
    #pragma unroll
    for (int i=0;i<4;++i)
      inv[i] = 1.0f / (acc_l0[i] + Lf[qg*16 + hi*4 + i]);
    size_t obase = (size_t)(b*SEQ + qt*128 + qg*32 + hi*4)*D_MODEL + h*64;
    #pragma unroll
    for (int i=0;i<4;++i){
      #pragma unroll
      for (int n=0;n<4;++n){
        float o = acc_o0[n][i] + Of[qg*1024 + (hi*4+i)*64 + n*16 + c];
        AO[obase + (size_t)i*D_MODEL + n*16 + c] = f2bf(o * inv[i]);
      }
    }
  }
  __syncthreads();
  // ---- pass qh = 1 ----
  if (kh == 1){
    #pragma unroll
    for (int n=0;n<4;++n)
      #pragma unroll
      for (int i=0;i<4;++i)
        Of[qg*1024 + (hi*4+i)*64 + n*16 + c] = acc_o1[n][i];
    if (c == 0){
      #pragma unroll
      for (int i=0;i<4;++i) Lf[qg*16 + hi*4 + i] = acc_l1[i];
    }
  }
  __syncthreads();
  if (kh == 0){
    float inv[4];
    #pragma unroll
    for (int i=0;i<4;++i)
      inv[i] = 1.0f / (acc_l1[i] + Lf[qg*16 + hi*4 + i]);
    size_t obase = (size_t)(b*SEQ + qt*128 + qg*32 + 16 + hi*4)*D_MODEL + h*64;
    #pragma unroll
    for (int i=0;i<4;++i){
      #pragma unroll
      for (int n=0;n<4;++n){
        float o = acc_o1[n][i] + Of[qg*1024 + (hi*4+i)*64 + n*16 + c];
        AO[obase + (size_t)i*D_MODEL + n*16 + c] = f2bf(o * inv[i]);
      }
    }
  }
}

extern "C" void kernel_launch(void* const* d_in, const int* in_sizes, int n_in,
                              void* d_out, int out_size, void* d_ws, size_t ws_size,
                              hipStream_t stream)
{
  const float* X  = (const float*)d_in[0];
  const float* Wq = (const float*)d_in[1];
  const float* Wk = (const float*)d_in[2];
  const float* Wv = (const float*)d_in[3];
  const float* W0 = (const float*)d_in[4];
  float* out = (float*)d_out;

  char* ws = (char*)d_ws;
  const size_t MB = 1024*1024;
  u16* Xb    = (u16*)(ws);           // 8 MB  [4096][1024]; reused as AO later
  u16* WqkvT = (u16*)(ws +  8*MB);   // 6 MB  [3072][1024] (Wq,Wk,Wv rows)
  u16* W0T   = (u16*)(ws + 14*MB);   // 2 MB
  u16* QKVb  = (u16*)(ws + 16*MB);   // 24 MB [4096][3072]
  u16* Vt    = (u16*)(ws + 40*MB);   // 8 MB  [B*H][64][SEQ] (keys permuted)
  u16* AO    = Xb;                   // Xb dead after QKV GEMM

  const float scaleQ = 1.4426950408889634f / sqrtf((float)SEQ);
  const int M = BATCH*SEQ;

  k_cvt<<<dim3((M*D_MODEL/4 + 255)/256), 256, 0, stream>>>(X, Xb, M*D_MODEL/4);
  k_cvt_w_t<<<dim3(16,16,4), 256, 0, stream>>>(
      Wq, Wk, Wv, W0, WqkvT, WqkvT + 1024*1024, WqkvT + 2*1024*1024, W0T);
  k_gemm_qkv<<<dim3(3072/128, M/128), 256, 0, stream>>>(Xb, WqkvT, QKVb, scaleQ);
  k_trans_v<<<dim3(SEQ/64, BATCH*NH), 256, 0, stream>>>(QKVb, Vt);
  k_attn<<<dim3(BATCH*NH, SEQ/128), 512, 0, stream>>>(QKVb, Vt, AO);
  k_gemm_out<<<dim3(1024/128, M/128), 256, 0, stream>>>(AO, W0T, out);
}

// Round 10
// 110.441 us; speedup vs baseline: 1.2745x; 1.0624x over previous
//
#include <hip/hip_runtime.h>

#define D_MODEL 1024
#define SEQ     2048
#define BATCH   2
#define NH      16

using u16 = unsigned short;
typedef __bf16 bf16x8 __attribute__((ext_vector_type(8)));
typedef float  f32x4  __attribute__((ext_vector_type(4)));

__device__ __forceinline__ u16 f2bf(float f){
  union { __bf16 h; u16 u; } v; v.h = (__bf16)f; return v.u;
}

__device__ __forceinline__ void gload_lds16(const void* g, void* l){
  __builtin_amdgcn_global_load_lds(
      (const __attribute__((address_space(1))) void*)g,
      (__attribute__((address_space(3))) void*)l, 16, 0, 0);
}

// ---------- kernel 1: fp32 -> bf16 (X) ----------
__global__ __launch_bounds__(256) void k_cvt(const float* __restrict__ in,
                                             u16* __restrict__ out, int n4){
  int i = blockIdx.x*256 + threadIdx.x;
  if (i >= n4) return;
  float4 v = ((const float4*)in)[i];
  ushort4 o; o.x=f2bf(v.x); o.y=f2bf(v.y); o.z=f2bf(v.z); o.w=f2bf(v.w);
  ((ushort4*)out)[i] = o;
}

// ---------- kernel 2: weight fp32[K][N] -> bf16 transposed [N][K] ----------
__global__ __launch_bounds__(256) void k_cvt_w_t(
    const float* __restrict__ wq, const float* __restrict__ wk,
    const float* __restrict__ wv, const float* __restrict__ w0,
    u16* __restrict__ oq, u16* __restrict__ ok,
    u16* __restrict__ ov, u16* __restrict__ o0){
  const float* W; u16* O;
  if      (blockIdx.z==0){W=wq;O=oq;}
  else if (blockIdx.z==1){W=wk;O=ok;}
  else if (blockIdx.z==2){W=wv;O=ov;}
  else               {W=w0;O=o0;}
  __shared__ float T[64][65];
  int t = threadIdx.x;
  int r0 = t>>4, cb = (t&15)*4;
  int kt = blockIdx.y*64, nt = blockIdx.x*64;
  #pragma unroll
  for (int j=0;j<4;++j){
    int r = r0 + j*16;
    float4 v = *(const float4*)(W + (size_t)(kt + r)*1024 + nt + cb);
    T[r][cb] = v.x; T[r][cb+1] = v.y; T[r][cb+2] = v.z; T[r][cb+3] = v.w;
  }
  __syncthreads();
  #pragma unroll
  for (int j=0;j<4;++j){
    int rn = r0 + j*16;
    ushort4 o;
    o.x = f2bf(T[cb  ][rn]); o.y = f2bf(T[cb+1][rn]);
    o.z = f2bf(T[cb+2][rn]); o.w = f2bf(T[cb+3][rn]);
    *(ushort4*)(O + (size_t)(nt + rn)*1024 + kt + cb) = o;
  }
}

// ---------- kernel 3: fused QKV GEMM  QKV[M,3072] = X[M,1024] @ WqkvT^T ----
// 128x128 tile, 2-phase dbuf, XCD-swizzled blockIdx (nwg=768, %8==0).
__global__ __launch_bounds__(256) void k_gemm_qkv(
    const u16* __restrict__ A, const u16* __restrict__ Bt,
    u16* __restrict__ Ob, float scaleQ)
{
  const int K = 1024, N = 3072;
  const int nwg = gridDim.x * gridDim.y;
  const int f = blockIdx.y * gridDim.x + blockIdx.x;
  const int sw = (f & 7) * (nwg >> 3) + (f >> 3);
  const int bxs = sw % gridDim.x, bys = sw / gridDim.x;
  const int bm = bys*128, bn = bxs*128;
  const float scl = (bn < 1024) ? scaleQ : 1.0f;
  const int lane = threadIdx.x & 63, w = threadIdx.x >> 6;
  const int hi = lane >> 4, c = lane & 15;
  const int wr = w >> 1, wc = w & 1;

  __shared__ u16 As[2][128*32];
  __shared__ u16 Bs[2][128*32];

  const int i0 = 2*w, i1 = 2*w+1;
  const int rA0 = i0*16 + (lane>>2), rA1 = i1*16 + (lane>>2);
  const int cA  = (lane&3)*8;
  const u16* aS0 = A  + (size_t)(bm + rA0)*K + cA;
  const u16* aS1 = A  + (size_t)(bm + rA1)*K + cA;
  const u16* bS0 = Bt + (size_t)(bn + rA0)*K + cA;
  const u16* bS1 = Bt + (size_t)(bn + rA1)*K + cA;

  auto stage = [&](int buf, int kk){
    gload_lds16(aS0 + kk, As[buf] + i0*512);
    gload_lds16(aS1 + kk, As[buf] + i1*512);
    gload_lds16(bS0 + kk, Bs[buf] + i0*512);
    gload_lds16(bS1 + kk, Bs[buf] + i1*512);
  };

  f32x4 acc[4][4];
  #pragma unroll
  for (int mi=0;mi<4;++mi)
    #pragma unroll
    for (int ni=0;ni<4;++ni) acc[mi][ni] = (f32x4){0.f,0.f,0.f,0.f};

  stage(0, 0);
  __syncthreads();
  int cur = 0;
  for (int kk = 0; kk < K; kk += 32){
    if (kk + 32 < K) stage(cur^1, kk + 32);
    const u16* as = As[cur];
    const u16* bs = Bs[cur];
    bf16x8 af[4], bfr[4];
    #pragma unroll
    for (int mi=0;mi<4;++mi)
      af[mi] = *(const bf16x8*)(as + (wr*64 + mi*16 + c)*32 + hi*8);
    #pragma unroll
    for (int ni=0;ni<4;++ni)
      bfr[ni] = *(const bf16x8*)(bs + (wc*64 + ni*16 + c)*32 + hi*8);
    #pragma unroll
    for (int mi=0;mi<4;++mi)
      #pragma unroll
      for (int ni=0;ni<4;++ni)
        acc[mi][ni] = __builtin_amdgcn_mfma_f32_16x16x32_bf16(af[mi], bfr[ni], acc[mi][ni], 0, 0, 0);
    __syncthreads();
    cur ^= 1;
  }
  #pragma unroll
  for (int mi=0;mi<4;++mi){
    #pragma unroll
    for (int ni=0;ni<4;++ni){
      int row = bm + wr*64 + mi*16 + hi*4;
      int col = bn + wc*64 + ni*16 + c;
      #pragma unroll
      for (int r=0;r<4;++r)
        Ob[(size_t)(row + r)*N + col] = f2bf(acc[mi][ni][r] * scl);
    }
  }
}

// ---------- kernel 6: out-proj GEMM  C[M,1024] = AO @ W0T^T (fp32 out) -----
// 128x128 tile, XCD-swizzled (nwg=256, %8==0).
__global__ __launch_bounds__(256) void k_gemm_out(
    const u16* __restrict__ A, const u16* __restrict__ Bt,
    float* __restrict__ OF)
{
  const int K = 1024, N = 1024;
  const int nwg = gridDim.x * gridDim.y;
  const int f = blockIdx.y * gridDim.x + blockIdx.x;
  const int sw = (f & 7) * (nwg >> 3) + (f >> 3);
  const int bxs = sw % gridDim.x, bys = sw / gridDim.x;
  const int bm = bys*128, bn = bxs*128;
  const int lane = threadIdx.x & 63, w = threadIdx.x >> 6;
  const int hi = lane >> 4, c = lane & 15;
  const int wr = w >> 1, wc = w & 1;

  __shared__ u16 As[2][128*32];
  __shared__ u16 Bs[2][128*32];

  const int i0 = 2*w, i1 = 2*w+1;
  const int rA0 = i0*16 + (lane>>2), rA1 = i1*16 + (lane>>2);
  const int cA  = (lane&3)*8;
  const u16* aS0 = A  + (size_t)(bm + rA0)*K + cA;
  const u16* aS1 = A  + (size_t)(bm + rA1)*K + cA;
  const u16* bS0 = Bt + (size_t)(bn + rA0)*K + cA;
  const u16* bS1 = Bt + (size_t)(bn + rA1)*K + cA;

  auto stage = [&](int buf, int kk){
    gload_lds16(aS0 + kk, As[buf] + i0*512);
    gload_lds16(aS1 + kk, As[buf] + i1*512);
    gload_lds16(bS0 + kk, Bs[buf] + i0*512);
    gload_lds16(bS1 + kk, Bs[buf] + i1*512);
  };

  f32x4 acc[4][4];
  #pragma unroll
  for (int mi=0;mi<4;++mi)
    #pragma unroll
    for (int ni=0;ni<4;++ni) acc[mi][ni] = (f32x4){0.f,0.f,0.f,0.f};

  stage(0, 0);
  __syncthreads();
  int cur = 0;
  for (int kk = 0; kk < K; kk += 32){
    if (kk + 32 < K) stage(cur^1, kk + 32);
    const u16* as = As[cur];
    const u16* bs = Bs[cur];
    bf16x8 af[4], bfr[4];
    #pragma unroll
    for (int mi=0;mi<4;++mi)
      af[mi] = *(const bf16x8*)(as + (wr*64 + mi*16 + c)*32 + hi*8);
    #pragma unroll
    for (int ni=0;ni<4;++ni)
      bfr[ni] = *(const bf16x8*)(bs + (wc*64 + ni*16 + c)*32 + hi*8);
    #pragma unroll
    for (int mi=0;mi<4;++mi)
      #pragma unroll
      for (int ni=0;ni<4;++ni)
        acc[mi][ni] = __builtin_amdgcn_mfma_f32_16x16x32_bf16(af[mi], bfr[ni], acc[mi][ni], 0, 0, 0);
    __syncthreads();
    cur ^= 1;
  }
  #pragma unroll
  for (int mi=0;mi<4;++mi){
    #pragma unroll
    for (int ni=0;ni<4;++ni){
      int row = bm + wr*64 + mi*16 + hi*4;
      int col = bn + wc*64 + ni*16 + c;
      #pragma unroll
      for (int r=0;r<4;++r)
        OF[(size_t)(row + r)*N + col] = acc[mi][ni][r];
    }
  }
}

// ---------- kernel 4: V (QKV col 2048+) -> Vt [B*H][64][S-permuted] --------
// Key order inside each 64-key tile is permuted: pos = [kh hi1 hi0 t j1 j0]
// for key s = [kh t hi1 hi0 j1 j0]. Each lane's PV B-fragment (8 keys:
// {t*16+hi*4+j, t=0,1}) is one contiguous 16B block -> conflict-free b128,
// and the enumeration matches the 16x16x32 MFMA A/B k-order exactly.
__global__ __launch_bounds__(256) void k_trans_v(const u16* __restrict__ QKV,
                                                 u16* __restrict__ Vt){
  int st = blockIdx.x, bh = blockIdx.y;
  int b = bh >> 4, h = bh & 15;
  __shared__ u16 T[64][80];
  int t = threadIdx.x;
  {
    int s = t >> 2, dc = (t & 3)*16;
    const u16* src = QKV + (size_t)(b*SEQ + st*64 + s)*3072 + 2048 + h*64 + dc;
    *(uint4*)&T[s][dc]   = *(const uint4*)(src);
    *(uint4*)&T[s][dc+8] = *(const uint4*)(src + 8);
  }
  __syncthreads();
  {
    int d = t >> 2, sc = (t & 3)*16;
    u16* dst = Vt + ((size_t)bh*64 + d)*SEQ + st*64 + sc;
    u16 vals[16];
    #pragma unroll
    for (int x=0;x<16;++x){
      int p = sc + x;
      int s = (p & 0x23) | ((p & 0x04) << 2) | ((p & 0x18) >> 1);
      vals[x] = T[s][d];
    }
    uint4 w0, w1;
    w0.x = (unsigned)vals[ 0] | ((unsigned)vals[ 1] << 16);
    w0.y = (unsigned)vals[ 2] | ((unsigned)vals[ 3] << 16);
    w0.z = (unsigned)vals[ 4] | ((unsigned)vals[ 5] << 16);
    w0.w = (unsigned)vals[ 6] | ((unsigned)vals[ 7] << 16);
    w1.x = (unsigned)vals[ 8] | ((unsigned)vals[ 9] << 16);
    w1.y = (unsigned)vals[10] | ((unsigned)vals[11] << 16);
    w1.z = (unsigned)vals[12] | ((unsigned)vals[13] << 16);
    w1.w = (unsigned)vals[14] | ((unsigned)vals[15] << 16);
    *(uint4*)(dst)     = w0;
    *(uint4*)(dst + 8) = w1;
  }
}

// ---------- kernel 5: attention ----------
// 32 q-rows per wave; 8 waves (4qg x 2kh); grid (bh, qt) head-affine.
// SWAPPED QK^T (mfma(K,Q)); exp2 in-register packed DIRECTLY as the
// 16x16x32 A-fragment under key-enum k=hi*8+j -> key kh*32+(j>=4)*16+hi*4+
// (j&3); Vt's permutation delivers V B-frags in the same enum, so PV is
// 8 MFMA32 (was 16 MFMA16) and lsum 2 MFMA32 (was 4): 28 -> 18 MFMA/body.
__global__ __launch_bounds__(512, 4) void k_attn(const u16* __restrict__ QKV,
                                                 const u16* __restrict__ Vt,
                                                 u16* __restrict__ AO)
{
  const int bh = blockIdx.x, qt = blockIdx.y;
  const int b = bh >> 4, h = bh & 15;
  const int lane = threadIdx.x & 63, w = threadIdx.x >> 6;
  const int qg = w >> 1, kh = w & 1;
  const int hi = lane >> 4, c = lane & 15;

  __shared__ u16 Ks[2][64*64];   // [key][dim] rows 128B, source-swizzled
  __shared__ u16 Vs[2][64*64];   // [dim][key'] rows 128B, source-swizzled

  const size_t qbase = (size_t)(b*SEQ + qt*128 + qg*32 + c);
  const bf16x8 qA0 = *(const bf16x8*)(QKV + (qbase     )*3072 + h*64 + hi*8);
  const bf16x8 qA1 = *(const bf16x8*)(QKV + (qbase     )*3072 + h*64 + 32 + hi*8);
  const bf16x8 qB0 = *(const bf16x8*)(QKV + (qbase + 16)*3072 + h*64 + hi*8);
  const bf16x8 qB1 = *(const bf16x8*)(QKV + (qbase + 16)*3072 + h*64 + 32 + hi*8);

  bf16x8 ones8;
  #pragma unroll
  for (int j=0;j<8;++j) ones8[j] = (__bf16)1.0f;

  f32x4 acc_o0[4], acc_o1[4];
  #pragma unroll
  for (int n=0;n<4;++n){ acc_o0[n] = (f32x4){0.f,0.f,0.f,0.f};
                         acc_o1[n] = (f32x4){0.f,0.f,0.f,0.f}; }
  f32x4 acc_l0 = (f32x4){0.f,0.f,0.f,0.f};
  f32x4 acc_l1 = (f32x4){0.f,0.f,0.f,0.f};

  // staging: wave w loads rows w*8..w*8+7 of the 64-row K tile and V tile
  const int r = w*8 + (lane>>3);
  const int sb = ((((lane&7)*16) ^ ((lane>>3)<<4)) >> 1);  // u16 units
  const u16* kSrc = QKV + (size_t)(b*SEQ + r)*3072 + 1024 + h*64 + sb;
  const u16* vSrc = Vt + ((size_t)bh*64 + r)*SEQ + sb;

  auto stage = [&](int buf){
    gload_lds16(kSrc, Ks[buf] + w*512);
    gload_lds16(vSrc, Vs[buf] + w*512);
    kSrc += (size_t)64*3072; vSrc += 64;
  };

  // hoisted LDS read bases; XOR applied to full byte-within-row offset
  const int swz = ((c&7)<<4);
  const char* kr0 = (const char*)&Ks[0][0] + (kh*32 + c)*128 + (( 0 + hi*16) ^ swz);
  const char* kr1 = (const char*)&Ks[0][0] + (kh*32 + c)*128 + ((64 + hi*16) ^ swz);
  const char* vr  = (const char*)&Vs[0][0] + c*128 + ((kh*64 + hi*16) ^ swz);

  auto body = [&](int buf){
    const int bo = buf*8192;
    bf16x8 k00 = *(const bf16x8*)(kr0 + bo);          // keys t0, dims 0-31
    bf16x8 k01 = *(const bf16x8*)(kr1 + bo);          // keys t0, dims 32-63
    bf16x8 k10 = *(const bf16x8*)(kr0 + bo + 2048);   // keys t1, dims 0-31
    bf16x8 k11 = *(const bf16x8*)(kr1 + bo + 2048);   // keys t1, dims 32-63
    f32x4 s00 = (f32x4){0.f,0.f,0.f,0.f};  // t0, qh0
    f32x4 s10 = (f32x4){0.f,0.f,0.f,0.f};  // t1, qh0
    f32x4 s01 = (f32x4){0.f,0.f,0.f,0.f};  // t0, qh1
    f32x4 s11 = (f32x4){0.f,0.f,0.f,0.f};  // t1, qh1
    __builtin_amdgcn_s_setprio(1);
    s00 = __builtin_amdgcn_mfma_f32_16x16x32_bf16(k00, qA0, s00, 0,0,0);
    s10 = __builtin_amdgcn_mfma_f32_16x16x32_bf16(k10, qA0, s10, 0,0,0);
    s01 = __builtin_amdgcn_mfma_f32_16x16x32_bf16(k00, qB0, s01, 0,0,0);
    s11 = __builtin_amdgcn_mfma_f32_16x16x32_bf16(k10, qB0, s11, 0,0,0);
    s00 = __builtin_amdgcn_mfma_f32_16x16x32_bf16(k01, qA1, s00, 0,0,0);
    s10 = __builtin_amdgcn_mfma_f32_16x16x32_bf16(k11, qA1, s10, 0,0,0);
    s01 = __builtin_amdgcn_mfma_f32_16x16x32_bf16(k01, qB1, s01, 0,0,0);
    s11 = __builtin_amdgcn_mfma_f32_16x16x32_bf16(k11, qB1, s11, 0,0,0);
    __builtin_amdgcn_s_setprio(0);

    // exp2 packed directly as 16x16x32 A-frags: [t0 x4 | t1 x4] per lane
    bf16x8 a0, a1;
    #pragma unroll
    for (int i=0;i<4;++i){
      a0[i]   = (__bf16)__builtin_amdgcn_exp2f(s00[i]);
      a0[i+4] = (__bf16)__builtin_amdgcn_exp2f(s10[i]);
      a1[i]   = (__bf16)__builtin_amdgcn_exp2f(s01[i]);
      a1[i+4] = (__bf16)__builtin_amdgcn_exp2f(s11[i]);
    }

    __builtin_amdgcn_s_setprio(1);
    acc_l0 = __builtin_amdgcn_mfma_f32_16x16x32_bf16(a0, ones8, acc_l0, 0,0,0);
    acc_l1 = __builtin_amdgcn_mfma_f32_16x16x32_bf16(a1, ones8, acc_l1, 0,0,0);
    #pragma unroll
    for (int n=0;n<4;++n){
      bf16x8 vv = *(const bf16x8*)(vr + bo + n*2048);
      acc_o0[n] = __builtin_amdgcn_mfma_f32_16x16x32_bf16(a0, vv, acc_o0[n], 0,0,0);
      acc_o1[n] = __builtin_amdgcn_mfma_f32_16x16x32_bf16(a1, vv, acc_o1[n], 0,0,0);
    }
    __builtin_amdgcn_s_setprio(0);
  };

  stage(0);
  __syncthreads();
  #pragma unroll 1
  for (int u = 0; u < SEQ/128; ++u){
    stage(1);
    body(0);
    __syncthreads();
    if (u != SEQ/128 - 1) stage(0);
    body(1);
    __syncthreads();
  }

  // merge key-halves additively, one qh pass at a time (Of = 16KB in Ks)
  float* Of = (float*)&Ks[0][0];           // [qg][16][64] f32
  float* Lf = (float*)&Vs[0][0];           // [qg][16]
  // ---- pass qh = 0 ----
  if (kh == 1){
    #pragma unroll
    for (int n=0;n<4;++n)
      #pragma unroll
      for (int i=0;i<4;++i)
        Of[qg*1024 + (hi*4+i)*64 + n*16 + c] = acc_o0[n][i];
    if (c == 0){
      #pragma unroll
      for (int i=0;i<4;++i) Lf[qg*16 + hi*4 + i] = acc_l0[i];
    }
  }
  __syncthreads();
  if (kh == 0){
    float inv[4];
    #pragma unroll
    for (int i=0;i<4;++i)
      inv[i] = 1.0f / (acc_l0[i] + Lf[qg*16 + hi*4 + i]);
    size_t obase = (size_t)(b*SEQ + qt*128 + qg*32 + hi*4)*D_MODEL + h*64;
    #pragma unroll
    for (int i=0;i<4;++i){
      #pragma unroll
      for (int n=0;n<4;++n){
        float o = acc_o0[n][i] + Of[qg*1024 + (hi*4+i)*64 + n*16 + c];
        AO[obase + (size_t)i*D_MODEL + n*16 + c] = f2bf(o * inv[i]);
      }
    }
  }
  __syncthreads();
  // ---- pass qh = 1 ----
  if (kh == 1){
    #pragma unroll
    for (int n=0;n<4;++n)
      #pragma unroll
      for (int i=0;i<4;++i)
        Of[qg*1024 + (hi*4+i)*64 + n*16 + c] = acc_o1[n][i];
    if (c == 0){
      #pragma unroll
      for (int i=0;i<4;++i) Lf[qg*16 + hi*4 + i] = acc_l1[i];
    }
  }
  __syncthreads();
  if (kh == 0){
    float inv[4];
    #pragma unroll
    for (int i=0;i<4;++i)
      inv[i] = 1.0f / (acc_l1[i] + Lf[qg*16 + hi*4 + i]);
    size_t obase = (size_t)(b*SEQ + qt*128 + qg*32 + 16 + hi*4)*D_MODEL + h*64;
    #pragma unroll
    for (int i=0;i<4;++i){
      #pragma unroll
      for (int n=0;n<4;++n){
        float o = acc_o1[n][i] + Of[qg*1024 + (hi*4+i)*64 + n*16 + c];
        AO[obase + (size_t)i*D_MODEL + n*16 + c] = f2bf(o * inv[i]);
      }
    }
  }
}

extern "C" void kernel_launch(void* const* d_in, const int* in_sizes, int n_in,
                              void* d_out, int out_size, void* d_ws, size_t ws_size,
                              hipStream_t stream)
{
  const float* X  = (const float*)d_in[0];
  const float* Wq = (const float*)d_in[1];
  const float* Wk = (const float*)d_in[2];
  const float* Wv = (const float*)d_in[3];
  const float* W0 = (const float*)d_in[4];
  float* out = (float*)d_out;

  char* ws = (char*)d_ws;
  const size_t MB = 1024*1024;
  u16* Xb    = (u16*)(ws);           // 8 MB  [4096][1024]; reused as AO later
  u16* WqkvT = (u16*)(ws +  8*MB);   // 6 MB  [3072][1024] (Wq,Wk,Wv rows)
  u16* W0T   = (u16*)(ws + 14*MB);   // 2 MB
  u16* QKVb  = (u16*)(ws + 16*MB);   // 24 MB [4096][3072]
  u16* Vt    = (u16*)(ws + 40*MB);   // 8 MB  [B*H][64][SEQ] (keys permuted)
  u16* AO    = Xb;                   // Xb dead after QKV GEMM

  const float scaleQ = 1.4426950408889634f / sqrtf((float)SEQ);
  const int M = BATCH*SEQ;

  k_cvt<<<dim3((M*D_MODEL/4 + 255)/256), 256, 0, stream>>>(X, Xb, M*D_MODEL/4);
  k_cvt_w_t<<<dim3(16,16,4), 256, 0, stream>>>(
      Wq, Wk, Wv, W0, WqkvT, WqkvT + 1024*1024, WqkvT + 2*1024*1024, W0T);
  k_gemm_qkv<<<dim3(3072/128, M/128), 256, 0, stream>>>(Xb, WqkvT, QKVb, scaleQ);
  k_trans_v<<<dim3(SEQ/64, BATCH*NH), 256, 0, stream>>>(QKVb, Vt);
  k_attn<<<dim3(BATCH*NH, SEQ/128), 512, 0, stream>>>(QKVb, Vt, AO);
  k_gemm_out<<<dim3(1024/128, M/128), 256, 0, stream>>>(AO, W0T, out);
}

// Round 11
// 107.233 us; speedup vs baseline: 1.3126x; 1.0299x over previous
//
#include <hip/hip_runtime.h>

#define D_MODEL 1024
#define SEQ     2048
#define BATCH   2
#define NH      16

using u16 = unsigned short;
typedef __bf16 bf16x8 __attribute__((ext_vector_type(8)));
typedef float  f32x4  __attribute__((ext_vector_type(4)));

__device__ __forceinline__ u16 f2bf(float f){
  union { __bf16 h; u16 u; } v; v.h = (__bf16)f; return v.u;
}

__device__ __forceinline__ void gload_lds16(const void* g, void* l){
  __builtin_amdgcn_global_load_lds(
      (const __attribute__((address_space(1))) void*)g,
      (__attribute__((address_space(3))) void*)l, 16, 0, 0);
}

// ---------- kernel 1+2 merged: X fp32->bf16  AND  weights ->bf16 [N][K] ----
__global__ __launch_bounds__(256) void k_prep(
    const float* __restrict__ X, u16* __restrict__ Xb,
    const float* __restrict__ wq, const float* __restrict__ wk,
    const float* __restrict__ wv, const float* __restrict__ w0,
    u16* __restrict__ oq, u16* __restrict__ ok,
    u16* __restrict__ ov, u16* __restrict__ o0)
{
  const int t = threadIdx.x;
  if (blockIdx.x < 4096){
    int i = blockIdx.x*256 + t;
    float4 v = ((const float4*)X)[i];
    ushort4 o; o.x=f2bf(v.x); o.y=f2bf(v.y); o.z=f2bf(v.z); o.w=f2bf(v.w);
    ((ushort4*)Xb)[i] = o;
    return;
  }
  const int bid = blockIdx.x - 4096;
  const int z = bid >> 8, rem = bid & 255;
  const int nt = (rem & 15)*64, kt = (rem >> 4)*64;
  const float* W; u16* O;
  if      (z==0){W=wq;O=oq;}
  else if (z==1){W=wk;O=ok;}
  else if (z==2){W=wv;O=ov;}
  else          {W=w0;O=o0;}
  __shared__ float T[64][65];
  int r0 = t>>4, cb = (t&15)*4;
  #pragma unroll
  for (int j=0;j<4;++j){
    int r = r0 + j*16;
    float4 v = *(const float4*)(W + (size_t)(kt + r)*1024 + nt + cb);
    T[r][cb] = v.x; T[r][cb+1] = v.y; T[r][cb+2] = v.z; T[r][cb+3] = v.w;
  }
  __syncthreads();
  #pragma unroll
  for (int j=0;j<4;++j){
    int rn = r0 + j*16;
    ushort4 o;
    o.x = f2bf(T[cb  ][rn]); o.y = f2bf(T[cb+1][rn]);
    o.z = f2bf(T[cb+2][rn]); o.w = f2bf(T[cb+3][rn]);
    *(ushort4*)(O + (size_t)(nt + rn)*1024 + kt + cb) = o;
  }
}

// ---------- kernel 3: fused QKV GEMM  QKV[M,3072] = X[M,1024] @ WqkvT^T ----
// 128x128 tile, 2-phase dbuf, XCD-swizzled blockIdx (nwg=768, %8==0).
__global__ __launch_bounds__(256) void k_gemm_qkv(
    const u16* __restrict__ A, const u16* __restrict__ Bt,
    u16* __restrict__ Ob, float scaleQ)
{
  const int K = 1024, N = 3072;
  const int nwg = gridDim.x * gridDim.y;
  const int f = blockIdx.y * gridDim.x + blockIdx.x;
  const int sw = (f & 7) * (nwg >> 3) + (f >> 3);
  const int bxs = sw % gridDim.x, bys = sw / gridDim.x;
  const int bm = bys*128, bn = bxs*128;
  const float scl = (bn < 1024) ? scaleQ : 1.0f;
  const int lane = threadIdx.x & 63, w = threadIdx.x >> 6;
  const int hi = lane >> 4, c = lane & 15;
  const int wr = w >> 1, wc = w & 1;

  __shared__ u16 As[2][128*32];
  __shared__ u16 Bs[2][128*32];

  const int i0 = 2*w, i1 = 2*w+1;
  const int rA0 = i0*16 + (lane>>2), rA1 = i1*16 + (lane>>2);
  const int cA  = (lane&3)*8;
  const u16* aS0 = A  + (size_t)(bm + rA0)*K + cA;
  const u16* aS1 = A  + (size_t)(bm + rA1)*K + cA;
  const u16* bS0 = Bt + (size_t)(bn + rA0)*K + cA;
  const u16* bS1 = Bt + (size_t)(bn + rA1)*K + cA;

  auto stage = [&](int buf, int kk){
    gload_lds16(aS0 + kk, As[buf] + i0*512);
    gload_lds16(aS1 + kk, As[buf] + i1*512);
    gload_lds16(bS0 + kk, Bs[buf] + i0*512);
    gload_lds16(bS1 + kk, Bs[buf] + i1*512);
  };

  f32x4 acc[4][4];
  #pragma unroll
  for (int mi=0;mi<4;++mi)
    #pragma unroll
    for (int ni=0;ni<4;++ni) acc[mi][ni] = (f32x4){0.f,0.f,0.f,0.f};

  stage(0, 0);
  __syncthreads();
  int cur = 0;
  for (int kk = 0; kk < K; kk += 32){
    if (kk + 32 < K) stage(cur^1, kk + 32);
    const u16* as = As[cur];
    const u16* bs = Bs[cur];
    bf16x8 af[4], bfr[4];
    #pragma unroll
    for (int mi=0;mi<4;++mi)
      af[mi] = *(const bf16x8*)(as + (wr*64 + mi*16 + c)*32 + hi*8);
    #pragma unroll
    for (int ni=0;ni<4;++ni)
      bfr[ni] = *(const bf16x8*)(bs + (wc*64 + ni*16 + c)*32 + hi*8);
    #pragma unroll
    for (int mi=0;mi<4;++mi)
      #pragma unroll
      for (int ni=0;ni<4;++ni)
        acc[mi][ni] = __builtin_amdgcn_mfma_f32_16x16x32_bf16(af[mi], bfr[ni], acc[mi][ni], 0, 0, 0);
    __syncthreads();
    cur ^= 1;
  }
  #pragma unroll
  for (int mi=0;mi<4;++mi){
    #pragma unroll
    for (int ni=0;ni<4;++ni){
      int row = bm + wr*64 + mi*16 + hi*4;
      int col = bn + wc*64 + ni*16 + c;
      #pragma unroll
      for (int r=0;r<4;++r)
        Ob[(size_t)(row + r)*N + col] = f2bf(acc[mi][ni][r] * scl);
    }
  }
}

// ---------- kernel 6: out-proj GEMM  C[M,1024] = AO @ W0T^T (fp32 out) -----
// 128x128 tile, XCD-swizzled (nwg=256, %8==0).
__global__ __launch_bounds__(256) void k_gemm_out(
    const u16* __restrict__ A, const u16* __restrict__ Bt,
    float* __restrict__ OF)
{
  const int K = 1024, N = 1024;
  const int nwg = gridDim.x * gridDim.y;
  const int f = blockIdx.y * gridDim.x + blockIdx.x;
  const int sw = (f & 7) * (nwg >> 3) + (f >> 3);
  const int bxs = sw % gridDim.x, bys = sw / gridDim.x;
  const int bm = bys*128, bn = bxs*128;
  const int lane = threadIdx.x & 63, w = threadIdx.x >> 6;
  const int hi = lane >> 4, c = lane & 15;
  const int wr = w >> 1, wc = w & 1;

  __shared__ u16 As[2][128*32];
  __shared__ u16 Bs[2][128*32];

  const int i0 = 2*w, i1 = 2*w+1;
  const int rA0 = i0*16 + (lane>>2), rA1 = i1*16 + (lane>>2);
  const int cA  = (lane&3)*8;
  const u16* aS0 = A  + (size_t)(bm + rA0)*K + cA;
  const u16* aS1 = A  + (size_t)(bm + rA1)*K + cA;
  const u16* bS0 = Bt + (size_t)(bn + rA0)*K + cA;
  const u16* bS1 = Bt + (size_t)(bn + rA1)*K + cA;

  auto stage = [&](int buf, int kk){
    gload_lds16(aS0 + kk, As[buf] + i0*512);
    gload_lds16(aS1 + kk, As[buf] + i1*512);
    gload_lds16(bS0 + kk, Bs[buf] + i0*512);
    gload_lds16(bS1 + kk, Bs[buf] + i1*512);
  };

  f32x4 acc[4][4];
  #pragma unroll
  for (int mi=0;mi<4;++mi)
    #pragma unroll
    for (int ni=0;ni<4;++ni) acc[mi][ni] = (f32x4){0.f,0.f,0.f,0.f};

  stage(0, 0);
  __syncthreads();
  int cur = 0;
  for (int kk = 0; kk < K; kk += 32){
    if (kk + 32 < K) stage(cur^1, kk + 32);
    const u16* as = As[cur];
    const u16* bs = Bs[cur];
    bf16x8 af[4], bfr[4];
    #pragma unroll
    for (int mi=0;mi<4;++mi)
      af[mi] = *(const bf16x8*)(as + (wr*64 + mi*16 + c)*32 + hi*8);
    #pragma unroll
    for (int ni=0;ni<4;++ni)
      bfr[ni] = *(const bf16x8*)(bs + (wc*64 + ni*16 + c)*32 + hi*8);
    #pragma unroll
    for (int mi=0;mi<4;++mi)
      #pragma unroll
      for (int ni=0;ni<4;++ni)
        acc[mi][ni] = __builtin_amdgcn_mfma_f32_16x16x32_bf16(af[mi], bfr[ni], acc[mi][ni], 0, 0, 0);
    __syncthreads();
    cur ^= 1;
  }
  #pragma unroll
  for (int mi=0;mi<4;++mi){
    #pragma unroll
    for (int ni=0;ni<4;++ni){
      int row = bm + wr*64 + mi*16 + hi*4;
      int col = bn + wc*64 + ni*16 + c;
      #pragma unroll
      for (int r=0;r<4;++r)
        OF[(size_t)(row + r)*N + col] = acc[mi][ni][r];
    }
  }
}

// ---------- kernel 4: V (QKV col 2048+) -> Vt [B*H][64][S-permuted] --------
// Key order inside each 64-key tile is permuted: pos = [kh hi1 hi0 t j1 j0]
// for key s = [kh t hi1 hi0 j1 j0]. Each lane's PV B-fragment (8 keys:
// {t*16+hi*4+j, t=0,1}) is one contiguous 16B block -> conflict-free b128,
// and the enumeration matches the 16x16x32 MFMA A/B k-order exactly.
__global__ __launch_bounds__(256) void k_trans_v(const u16* __restrict__ QKV,
                                                 u16* __restrict__ Vt){
  int st = blockIdx.x, bh = blockIdx.y;
  int b = bh >> 4, h = bh & 15;
  __shared__ u16 T[64][80];
  int t = threadIdx.x;
  {
    int s = t >> 2, dc = (t & 3)*16;
    const u16* src = QKV + (size_t)(b*SEQ + st*64 + s)*3072 + 2048 + h*64 + dc;
    *(uint4*)&T[s][dc]   = *(const uint4*)(src);
    *(uint4*)&T[s][dc+8] = *(const uint4*)(src + 8);
  }
  __syncthreads();
  {
    int d = t >> 2, sc = (t & 3)*16;
    u16* dst = Vt + ((size_t)bh*64 + d)*SEQ + st*64 + sc;
    u16 vals[16];
    #pragma unroll
    for (int x=0;x<16;++x){
      int p = sc + x;
      int s = (p & 0x23) | ((p & 0x04) << 2) | ((p & 0x18) >> 1);
      vals[x] = T[s][d];
    }
    uint4 w0, w1;
    w0.x = (unsigned)vals[ 0] | ((unsigned)vals[ 1] << 16);
    w0.y = (unsigned)vals[ 2] | ((unsigned)vals[ 3] << 16);
    w0.z = (unsigned)vals[ 4] | ((unsigned)vals[ 5] << 16);
    w0.w = (unsigned)vals[ 6] | ((unsigned)vals[ 7] << 16);
    w1.x = (unsigned)vals[ 8] | ((unsigned)vals[ 9] << 16);
    w1.y = (unsigned)vals[10] | ((unsigned)vals[11] << 16);
    w1.z = (unsigned)vals[12] | ((unsigned)vals[13] << 16);
    w1.w = (unsigned)vals[14] | ((unsigned)vals[15] << 16);
    *(uint4*)(dst)     = w0;
    *(uint4*)(dst + 8) = w1;
  }
}

// ---------- kernel 5: attention ----------
// 4 waves/block (256 thr) = 2 qg x 2 kh; 64 q-rows PER WAVE (4 qsub x 16).
// Halves block LDS-read traffic again vs R10 (same 8 b128/wave-body now
// serve 64q x 32k). VGPR ~190 -> launch_bounds(256,2), 2 blocks/CU.
// grid (bh, qt) head-affine; SWAPPED QK^T; exp2 packed as 16x16x32 A-frag;
// Vt pre-permuted; lsum via ones-MFMA; kh merge in 4 qsub passes.
__global__ __launch_bounds__(256, 2) void k_attn(const u16* __restrict__ QKV,
                                                 const u16* __restrict__ Vt,
                                                 u16* __restrict__ AO)
{
  const int bh = blockIdx.x, qt = blockIdx.y;
  const int b = bh >> 4, h = bh & 15;
  const int lane = threadIdx.x & 63, w = threadIdx.x >> 6;  // w = 0..3
  const int qg = w >> 1, kh = w & 1;
  const int hi = lane >> 4, c = lane & 15;

  __shared__ u16 Ks[2][64*64];   // [key][dim] rows 128B, source-swizzled
  __shared__ u16 Vs[2][64*64];   // [dim][key'] rows 128B, source-swizzled

  const size_t qrow0 = (size_t)(b*SEQ + qt*128 + qg*64 + c);
  bf16x8 qf0[4], qf1[4];
  #pragma unroll
  for (int s=0;s<4;++s){
    qf0[s] = *(const bf16x8*)(QKV + (qrow0 + s*16)*3072 + h*64 + hi*8);
    qf1[s] = *(const bf16x8*)(QKV + (qrow0 + s*16)*3072 + h*64 + 32 + hi*8);
  }

  bf16x8 ones8;
  #pragma unroll
  for (int j=0;j<8;++j) ones8[j] = (__bf16)1.0f;

  f32x4 acc_o[4][4];
  f32x4 acc_l[4];
  #pragma unroll
  for (int s=0;s<4;++s){
    acc_l[s] = (f32x4){0.f,0.f,0.f,0.f};
    #pragma unroll
    for (int n=0;n<4;++n) acc_o[s][n] = (f32x4){0.f,0.f,0.f,0.f};
  }

  // staging: wave w stages rows w*8..+7 (instr0) and 32+w*8..+7 (instr1)
  const int r0 = w*8 + (lane>>3);
  const int r1 = 32 + r0;
  const int sb = ((((lane&7)*16) ^ ((lane>>3)<<4)) >> 1);  // u16 units
  const u16* kS0 = QKV + (size_t)(b*SEQ + r0)*3072 + 1024 + h*64 + sb;
  const u16* kS1 = QKV + (size_t)(b*SEQ + r1)*3072 + 1024 + h*64 + sb;
  const u16* vS0 = Vt + ((size_t)bh*64 + r0)*SEQ + sb;
  const u16* vS1 = Vt + ((size_t)bh*64 + r1)*SEQ + sb;

  auto stage = [&](int buf){
    gload_lds16(kS0, Ks[buf] + w*512);
    gload_lds16(kS1, Ks[buf] + 2048 + w*512);
    gload_lds16(vS0, Vs[buf] + w*512);
    gload_lds16(vS1, Vs[buf] + 2048 + w*512);
    kS0 += (size_t)64*3072; kS1 += (size_t)64*3072; vS0 += 64; vS1 += 64;
  };

  // hoisted LDS read bases; XOR applied to full byte-within-row offset
  const int swz = ((c&7)<<4);
  const char* kr0 = (const char*)&Ks[0][0] + (kh*32 + c)*128 + (( 0 + hi*16) ^ swz);
  const char* kr1 = (const char*)&Ks[0][0] + (kh*32 + c)*128 + ((64 + hi*16) ^ swz);
  const char* vr  = (const char*)&Vs[0][0] + c*128 + ((kh*64 + hi*16) ^ swz);

  auto body = [&](int buf){
    const int bo = buf*8192;
    bf16x8 k00 = *(const bf16x8*)(kr0 + bo);          // keys t0, dims 0-31
    bf16x8 k01 = *(const bf16x8*)(kr1 + bo);          // keys t0, dims 32-63
    bf16x8 k10 = *(const bf16x8*)(kr0 + bo + 2048);   // keys t1, dims 0-31
    bf16x8 k11 = *(const bf16x8*)(kr1 + bo + 2048);   // keys t1, dims 32-63
    bf16x8 vv0 = *(const bf16x8*)(vr + bo);
    bf16x8 vv1 = *(const bf16x8*)(vr + bo + 2048);
    bf16x8 vv2 = *(const bf16x8*)(vr + bo + 4096);
    bf16x8 vv3 = *(const bf16x8*)(vr + bo + 6144);
    #pragma unroll
    for (int s=0;s<4;++s){
      f32x4 s0 = (f32x4){0.f,0.f,0.f,0.f};
      f32x4 s1 = (f32x4){0.f,0.f,0.f,0.f};
      __builtin_amdgcn_s_setprio(1);
      s0 = __builtin_amdgcn_mfma_f32_16x16x32_bf16(k00, qf0[s], s0, 0,0,0);
      s1 = __builtin_amdgcn_mfma_f32_16x16x32_bf16(k10, qf0[s], s1, 0,0,0);
      s0 = __builtin_amdgcn_mfma_f32_16x16x32_bf16(k01, qf1[s], s0, 0,0,0);
      s1 = __builtin_amdgcn_mfma_f32_16x16x32_bf16(k11, qf1[s], s1, 0,0,0);
      __builtin_amdgcn_s_setprio(0);
      bf16x8 a;
      #pragma unroll
      for (int i=0;i<4;++i){
        a[i]   = (__bf16)__builtin_amdgcn_exp2f(s0[i]);
        a[i+4] = (__bf16)__builtin_amdgcn_exp2f(s1[i]);
      }
      __builtin_amdgcn_s_setprio(1);
      acc_l[s]    = __builtin_amdgcn_mfma_f32_16x16x32_bf16(a, ones8, acc_l[s], 0,0,0);
      acc_o[s][0] = __builtin_amdgcn_mfma_f32_16x16x32_bf16(a, vv0, acc_o[s][0], 0,0,0);
      acc_o[s][1] = __builtin_amdgcn_mfma_f32_16x16x32_bf16(a, vv1, acc_o[s][1], 0,0,0);
      acc_o[s][2] = __builtin_amdgcn_mfma_f32_16x16x32_bf16(a, vv2, acc_o[s][2], 0,0,0);
      acc_o[s][3] = __builtin_amdgcn_mfma_f32_16x16x32_bf16(a, vv3, acc_o[s][3], 0,0,0);
      __builtin_amdgcn_s_setprio(0);
    }
  };

  stage(0);
  __syncthreads();
  #pragma unroll 1
  for (int u = 0; u < SEQ/128; ++u){
    stage(1);
    body(0);
    __syncthreads();
    if (u != SEQ/128 - 1) stage(0);
    body(1);
    __syncthreads();
  }

  // merge key-halves additively, one qsub pass at a time (Of = 8KB in Ks)
  float* Of = (float*)&Ks[0][0];           // [qg][16][64] f32
  float* Lf = (float*)&Vs[0][0];           // [qg][16]
  #pragma unroll
  for (int s=0;s<4;++s){
    if (kh == 1){
      #pragma unroll
      for (int n=0;n<4;++n)
        #pragma unroll
        for (int i=0;i<4;++i)
          Of[qg*1024 + (hi*4+i)*64 + n*16 + c] = acc_o[s][n][i];
      if (c == 0){
        #pragma unroll
        for (int i=0;i<4;++i) Lf[qg*16 + hi*4 + i] = acc_l[s][i];
      }
    }
    __syncthreads();
    if (kh == 0){
      float inv[4];
      #pragma unroll
      for (int i=0;i<4;++i)
        inv[i] = 1.0f / (acc_l[s][i] + Lf[qg*16 + hi*4 + i]);
      size_t obase = (size_t)(b*SEQ + qt*128 + qg*64 + s*16 + hi*4)*D_MODEL + h*64;
      #pragma unroll
      for (int i=0;i<4;++i){
        #pragma unroll
        for (int n=0;n<4;++n){
          float o = acc_o[s][n][i] + Of[qg*1024 + (hi*4+i)*64 + n*16 + c];
          AO[obase + (size_t)i*D_MODEL + n*16 + c] = f2bf(o * inv[i]);
        }
      }
    }
    __syncthreads();
  }
}

extern "C" void kernel_launch(void* const* d_in, const int* in_sizes, int n_in,
                              void* d_out, int out_size, void* d_ws, size_t ws_size,
                              hipStream_t stream)
{
  const float* X  = (const float*)d_in[0];
  const float* Wq = (const float*)d_in[1];
  const float* Wk = (const float*)d_in[2];
  const float* Wv = (const float*)d_in[3];
  const float* W0 = (const float*)d_in[4];
  float* out = (float*)d_out;

  char* ws = (char*)d_ws;
  const size_t MB = 1024*1024;
  u16* Xb    = (u16*)(ws);           // 8 MB  [4096][1024]; reused as AO later
  u16* WqkvT = (u16*)(ws +  8*MB);   // 6 MB  [3072][1024] (Wq,Wk,Wv rows)
  u16* W0T   = (u16*)(ws + 14*MB);   // 2 MB
  u16* QKVb  = (u16*)(ws + 16*MB);   // 24 MB [4096][3072]
  u16* Vt    = (u16*)(ws + 40*MB);   // 8 MB  [B*H][64][SEQ] (keys permuted)
  u16* AO    = Xb;                   // Xb dead after QKV GEMM

  const float scaleQ = 1.4426950408889634f / sqrtf((float)SEQ);
  const int M = BATCH*SEQ;

  k_prep<<<dim3(4096 + 1024), 256, 0, stream>>>(
      X, Xb, Wq, Wk, Wv, W0,
      WqkvT, WqkvT + 1024*1024, WqkvT + 2*1024*1024, W0T);
  k_gemm_qkv<<<dim3(3072/128, M/128), 256, 0, stream>>>(Xb, WqkvT, QKVb, scaleQ);
  k_trans_v<<<dim3(SEQ/64, BATCH*NH), 256, 0, stream>>>(QKVb, Vt);
  k_attn<<<dim3(BATCH*NH, SEQ/128), 256, 0, stream>>>(QKVb, Vt, AO);
  k_gemm_out<<<dim3(1024/128, M/128), 256, 0, stream>>>(AO, W0T, out);
}